// Round 6
// baseline (2319.878 us; speedup 1.0000x reference)
//
#include <hip/hip_runtime.h>
#include <hip/hip_bf16.h>
#include <math.h>

#define BB 128
#define TT 256
#define IDIM 64
#define HD 128
#define G4 512
#define OC 100
#define W1 62
#define W2 60
#define W3 58
#define NPX1 (W1*W1)
#define NPX2 (W2*W2)
#define NPX3 (W3*W3)
#define SS NPX3
#define FF (SS + 2*HD)
#define HIDN 1810
#define ANF 64
#define BC 32            // batch chunk for CNN branch

typedef __hip_bfloat16 bf16;
typedef __attribute__((ext_vector_type(8))) short bf16x8;
typedef __attribute__((ext_vector_type(4))) short bf16x4;
typedef __attribute__((ext_vector_type(4))) float f32x4;

__device__ __forceinline__ float ldf(const float* p) { return *p; }
__device__ __forceinline__ float ldf(const bf16* p)  { return __bfloat162float(*p); }
__device__ __forceinline__ void  stf(float* p, float v) { *p = v; }
__device__ __forceinline__ void  stf(bf16* p, float v)  { *p = __float2bfloat16(v); }

__device__ __forceinline__ short f2bs(float v) {
    bf16 t = __float2bfloat16(v); short s; __builtin_memcpy(&s, &t, 2); return s;
}
__device__ __forceinline__ float bs2f(short s) {
    unsigned u = ((unsigned)(unsigned short)s) << 16;
    float f; __builtin_memcpy(&f, &u, 4); return f;
}
__device__ __forceinline__ float fsig(float x) {
    return __builtin_amdgcn_rcpf(1.f + __expf(-x));
}
__device__ __forceinline__ float ftanh(float x) {
    float t = __expf(-2.f * fabsf(x));
    float r = __builtin_amdgcn_rcpf(1.f + t);
    float m = 1.f - 2.f * t * r;
    return copysignf(m, x);
}

__global__ void zero_kernel(float* o, int n)
{
    int i = blockIdx.x * 256 + threadIdx.x;
    if (i < n) o[i] = 0.f;
}

// ---------------- fp32 -> bf16 vectorized convert ----------------
__global__ __launch_bounds__(256)
void cvt4_bf16(const float* __restrict__ s, bf16* __restrict__ d, int n4)
{
    int i = blockIdx.x * 256 + threadIdx.x;
    if (i >= n4) return;
    float4 v = ((const float4*)s)[i];
    bf16x4 o;
    o[0] = f2bs(v.x); o[1] = f2bs(v.y); o[2] = f2bs(v.z); o[3] = f2bs(v.w);
    *(bf16x4*)(d + 4 * (size_t)i) = o;
}

// ---------------- conv1: [BC,3,64,64] -> relu -> [BC,100,62,62] (bf16 out) ----------------
__global__ __launch_bounds__(256)
void conv1_kernel(const float* __restrict__ x1,
                  const float* __restrict__ w,     // [100,3,3,3]
                  const float* __restrict__ bias,  // [100]
                  bf16* __restrict__ out)          // [BC,100,62,62]
{
    __shared__ float wl[2700];
    __shared__ float bl[OC];
    int tid = threadIdx.x;
    for (int i = tid; i < 2700; i += 256) wl[i] = w[i];
    if (tid < OC) bl[tid] = bias[tid];
    __syncthreads();
    int b  = blockIdx.x;
    int px = blockIdx.y * 256 + tid;
    if (px >= NPX1) return;
    int y = px / W1, x = px % W1;
    float in[3][3][3];
    const float* xb = x1 + (size_t)b * 3 * 64 * 64;
#pragma unroll
    for (int ic = 0; ic < 3; ic++)
#pragma unroll
        for (int r = 0; r < 3; r++)
#pragma unroll
            for (int c = 0; c < 3; c++)
                in[ic][r][c] = xb[(ic * 64 + y + r) * 64 + x + c];
    bf16* ob = out + (size_t)b * OC * NPX1 + px;
    for (int oc = 0; oc < OC; ++oc) {
        float acc = bl[oc];
        const float* wp = &wl[oc * 27];
#pragma unroll
        for (int ic = 0; ic < 3; ic++)
#pragma unroll
            for (int r = 0; r < 3; r++)
#pragma unroll
                for (int c = 0; c < 3; c++)
                    acc = fmaf(in[ic][r][c], wp[ic * 9 + r * 3 + c], acc);
        ob[(size_t)oc * NPX1] = __float2bfloat16(fmaxf(acc, 0.f));
    }
}

// ---------------- conv2 weight repack: fp32 [oc][ic][3][3] -> bf16 WT[t][s][oc112][i32] ----------------
__global__ __launch_bounds__(256)
void wt_repack(const float* __restrict__ w, bf16* __restrict__ WT)
{
    int idx = blockIdx.x * 256 + threadIdx.x;   // over 9*4*112*32 = 129024
    if (idx >= 129024) return;
    int i  = idx & 31;
    int oc = (idx >> 5) % 112;
    int ts = idx / (112 * 32);   // t*4+s
    int s = ts & 3, t = ts >> 2;
    int ic = s * 32 + i;
    float v = 0.f;
    if (oc < OC && ic < OC) v = w[(oc * OC + ic) * 9 + t];
    WT[idx] = __float2bfloat16(v);
}

// ---------------- Whh repack: fp32 [512,128] -> bf16 LW in A-fragment order ----------------
// group idx: hq(2b) | l16(4b) | s(2b) | gt(2b) | w(3b); 8 bf16 per group.
__global__ __launch_bounds__(256)
void whh_repack(const float* __restrict__ Whh, bf16* __restrict__ LW)
{
    int idx = blockIdx.x * 256 + threadIdx.x;   // 8192 groups
    if (idx >= 8192) return;
    int hq  = idx & 3;
    int l16 = (idx >> 2) & 15;
    int s   = (idx >> 6) & 3;
    int gt  = (idx >> 8) & 3;
    int w   = idx >> 10;
    const float* src = Whh + (size_t)(gt * 128 + w * 16 + l16) * 128 + s * 32 + hq * 8;
    float4 v0 = *(const float4*)src;
    float4 v1 = *(const float4*)(src + 4);
    bf16x8 f;
    f[0] = f2bs(v0.x); f[1] = f2bs(v0.y); f[2] = f2bs(v0.z); f[3] = f2bs(v0.w);
    f[4] = f2bs(v1.x); f[5] = f2bs(v1.y); f[6] = f2bs(v1.z); f[7] = f2bs(v1.w);
    *(bf16x8*)(LW + (size_t)idx * 8) = f;
}

// ---------------- conv2 via MFMA implicit GEMM (ic-contiguous LDS) ----------------
__global__ __launch_bounds__(256, 2)
void conv2_mfma(const bf16* __restrict__ in,   // [BC,100,iw,iw]
                const bf16* __restrict__ WT,   // [9][4][112][32] bf16
                const float* __restrict__ bias,
                bf16* __restrict__ out,        // [BC,100,ow,ow]
                int iw, int ow)
{
    __shared__ bf16 il[6 * 72 * 40];           // [r][x(72)][ic(pad 40)]
    int tid = threadIdx.x;
    int b = blockIdx.x;
    int y0 = blockIdx.y * 4;
    int wid = tid >> 6;
    int l = tid & 63;
    int hq = l >> 4;
    int l16 = l & 15;
    int yo = y0 + wid;

    f32x4 acc[7][4];
#pragma unroll
    for (int f = 0; f < 7; f++) {
#pragma unroll
        for (int r = 0; r < 4; r++) {
            int oc = f * 16 + hq * 4 + r;
            float bv = (oc < OC) ? bias[oc] : 0.f;
#pragma unroll
            for (int n = 0; n < 4; n++) acc[f][n][r] = bv;
        }
    }

    const size_t ims = (size_t)iw * iw;
    int icl = tid & 31;
    int t2  = tid >> 5;                        // 0..7
    for (int s = 0; s < 4; ++s) {
        __syncthreads();
        int ic = s * 32 + icl;
        bool icok = ic < OC;
        const bf16* ibase = in + (size_t)(b * OC + ic) * ims;
#pragma unroll
        for (int it = 0; it < 7; ++it) {
            int u2 = t2 + it * 8;              // 0..53 over (r:6, xb:9)
            if (u2 < 54) {
                int r = u2 / 9, xb = u2 - r * 9;
                int x8 = xb * 8;
                int yy = y0 + r;
                bf16x8 v = {0, 0, 0, 0, 0, 0, 0, 0};
                if (icok && yy < iw && x8 < iw) {
                    const short* sp = (const short*)(ibase + (size_t)yy * iw + x8);
                    if (x8 + 8 <= iw) {
                        const unsigned* sp32 = (const unsigned*)sp;
#pragma unroll
                        for (int q = 0; q < 4; q++)
                            ((unsigned*)&v)[q] = sp32[q];
                    } else {
                        for (int k = 0; k < 8; k++)
                            if (x8 + k < iw) ((short*)&v)[k] = sp[k];
                    }
                }
                bf16* dst = &il[(r * 72 + x8) * 40 + icl];
#pragma unroll
                for (int k = 0; k < 8; k++)
                    *(short*)&dst[k * 40] = ((short*)&v)[k];
            }
        }
        __syncthreads();

        const bf16* wts = WT + (size_t)s * 112 * 32;
#pragma unroll
        for (int ky = 0; ky < 3; ++ky) {
#pragma unroll
            for (int kx = 0; kx < 3; ++kx) {
                int t = ky * 3 + kx;
                uint4 a[7];
                const uint4* wp = (const uint4*)(wts + (size_t)t * 4 * 112 * 32);
#pragma unroll
                for (int f = 0; f < 7; f++)
                    a[f] = wp[(f * 16 + l16) * 4 + hq];
                bf16x8 bfr[4];
#pragma unroll
                for (int n = 0; n < 4; n++)
                    bfr[n] = *(const bf16x8*)&il[((wid + ky) * 72 + kx + l16 + n * 16) * 40 + hq * 8];
#pragma unroll
                for (int f = 0; f < 7; f++)
#pragma unroll
                    for (int n = 0; n < 4; n++)
                        acc[f][n] = __builtin_amdgcn_mfma_f32_16x16x32_bf16(
                            *(const bf16x8*)&a[f], bfr[n], acc[f][n], 0, 0, 0);
            }
        }
    }

    if (yo < ow) {
#pragma unroll
        for (int f = 0; f < 7; f++) {
#pragma unroll
            for (int r = 0; r < 4; r++) {
                int oc = f * 16 + hq * 4 + r;
                if (oc < OC) {
#pragma unroll
                    for (int n = 0; n < 4; n++) {
                        int x = n * 16 + l16;
                        if (x < ow)
                            out[((size_t)(b * OC + oc) * ow + yo) * ow + x] =
                                __float2bfloat16(fmaxf(acc[f][n][r], 0.f));
                    }
                }
            }
        }
    }
}

// ---------------- generic bf16 MFMA GEMM: C[M,N] = A[M,K] @ B[N,K]^T (+bias, +relu) ----------------
template<typename TC, int ACT>
__global__ __launch_bounds__(256)
void gemm_mfma(const bf16* __restrict__ A, int lda,
               const bf16* __restrict__ B, int ldb,
               const float* __restrict__ bias,
               TC* __restrict__ C, int ldc,
               int M, int N, int K)
{
    __shared__ bf16 As[64 * 72];
    __shared__ bf16 Bs[64 * 72];
    int tid = threadIdx.x;
    int l = tid & 63, wid = tid >> 6;
    int l16 = l & 15, h = l >> 4;
    int m0 = blockIdx.x * 64, n0 = blockIdx.y * 64;
    f32x4 acc[4];
#pragma unroll
    for (int nb = 0; nb < 4; nb++) acc[nb] = (f32x4){0.f, 0.f, 0.f, 0.f};

    int rs = tid >> 3;             // 0..31 staging row
    int kc = (tid & 7) * 8;        // 0..56 staging k-col

    for (int k0 = 0; k0 < K; k0 += 64) {
        int kr = K - k0;
#pragma unroll
        for (int half = 0; half < 2; half++) {
            int rr = rs + half * 32;
            bf16x8 av = {0, 0, 0, 0, 0, 0, 0, 0};
            int m = m0 + rr;
            if (m < M) {
                const short* src = (const short*)(A + (size_t)m * lda + k0 + kc);
                if (kc + 8 <= kr) av = *(const bf16x8*)src;
                else if (kc < kr) {
                    for (int j = 0; j < 8; j++) if (kc + j < kr) ((short*)&av)[j] = src[j];
                }
            }
            *(bf16x8*)&As[rr * 72 + kc] = av;
            bf16x8 bv = {0, 0, 0, 0, 0, 0, 0, 0};
            int n = n0 + rr;
            if (n < N) {
                const short* src = (const short*)(B + (size_t)n * ldb + k0 + kc);
                if (kc + 8 <= kr) bv = *(const bf16x8*)src;
                else if (kc < kr) {
                    for (int j = 0; j < 8; j++) if (kc + j < kr) ((short*)&bv)[j] = src[j];
                }
            }
            *(bf16x8*)&Bs[rr * 72 + kc] = bv;
        }
        __syncthreads();
#pragma unroll
        for (int kk = 0; kk < 2; kk++) {
            bf16x8 af = *(const bf16x8*)&As[(wid * 16 + l16) * 72 + kk * 32 + h * 8];
#pragma unroll
            for (int nb = 0; nb < 4; nb++) {
                bf16x8 bfr = *(const bf16x8*)&Bs[(nb * 16 + l16) * 72 + kk * 32 + h * 8];
                acc[nb] = __builtin_amdgcn_mfma_f32_16x16x32_bf16(af, bfr, acc[nb], 0, 0, 0);
            }
        }
        __syncthreads();
    }
#pragma unroll
    for (int nb = 0; nb < 4; nb++) {
        int col = n0 + nb * 16 + l16;
        if (col >= N) continue;
        float bv = bias ? bias[col] : 0.f;
#pragma unroll
        for (int reg = 0; reg < 4; reg++) {
            int row = m0 + wid * 16 + h * 4 + reg;
            if (row < M) {
                float v = acc[nb][reg] + bv;
                if (ACT == 1) v = fmaxf(v, 0.f);
                stf(&C[(size_t)row * ldc + col], v);
            }
        }
    }
}

// ---------------- small fp32 GEMM (kept for tiny HB matmul) ----------------
template<typename TA, typename TC, int BM, int BN, int BK, int TM, int TN, int ACT>
__global__ __launch_bounds__((BM / TM) * (BN / TN))
void gemm_tn(const TA* __restrict__ A, int lda,
             const float* __restrict__ Bmat, int ldb,
             const float* __restrict__ bias,
             TC* __restrict__ C, int ldc,
             int M, int N, int K)
{
    constexpr int TX = BN / TN;
    constexpr int TY = BM / TM;
    constexpr int NT = TX * TY;
    __shared__ float As[BK][BM + 1];
    __shared__ float Bs[BK][BN + 1];
    int tid = threadIdx.x;
    int tx = tid % TX, ty = tid / TX;
    int m0 = blockIdx.x * BM, n0 = blockIdx.y * BN;
    float acc[TM][TN] = {};
    for (int k0 = 0; k0 < K; k0 += BK) {
        for (int idx = tid; idx < BM * BK; idx += NT) {
            int i = idx / BK, j = idx % BK;
            int m = m0 + i, k = k0 + j;
            As[j][i] = (m < M && k < K) ? ldf(&A[(size_t)m * lda + k]) : 0.f;
        }
        for (int idx = tid; idx < BN * BK; idx += NT) {
            int i = idx / BK, j = idx % BK;
            int n = n0 + i, k = k0 + j;
            Bs[j][i] = (n < N && k < K) ? Bmat[(size_t)n * ldb + k] : 0.f;
        }
        __syncthreads();
#pragma unroll
        for (int k = 0; k < BK; ++k) {
            float av[TM], bv[TN];
#pragma unroll
            for (int i = 0; i < TM; i++) av[i] = As[k][ty * TM + i];
#pragma unroll
            for (int j = 0; j < TN; j++) bv[j] = Bs[k][tx * TN + j];
#pragma unroll
            for (int i = 0; i < TM; i++)
#pragma unroll
                for (int j = 0; j < TN; j++)
                    acc[i][j] += av[i] * bv[j];
        }
        __syncthreads();
    }
#pragma unroll
    for (int i = 0; i < TM; i++) {
        int m = m0 + ty * TM + i;
        if (m >= M) continue;
#pragma unroll
        for (int j = 0; j < TN; j++) {
            int n = n0 + tx * TN + j;
            if (n >= N) continue;
            float v = acc[i][j] + (bias ? bias[n] : 0.f);
            if (ACT == 1) v = fmaxf(v, 0.f);
            stf(&C[(size_t)m * ldc + n], v);
        }
    }
}

// ---------------- LSTM recurrence via MFMA, pre-packed weights in VGPRs ----------------
// 8 blocks x 512 thr; wave w owns gate-cols [16w,16w+16) of each gate tile.
// Double-buffered h in LDS -> single barrier per step.
__global__ __launch_bounds__(512, 1)
void lstm_mfma(const bf16* __restrict__ G,   // [B,T,512] x-part + biases
               const bf16* __restrict__ LW,  // packed Whh fragments
               bf16* __restrict__ Y,         // [B,T,128] or nullptr
               float* __restrict__ HN,       // [B,256]
               int hoff)
{
    __shared__ bf16 hbuf[2][16 * 136];
    int tid = threadIdx.x;
    int w = tid >> 6, l = tid & 63;
    int l16 = l & 15, hq = l >> 4;
    int b0 = blockIdx.x * 16;

    // A-fragments of Whh: 16 x b128 loads from the packed layout
    bf16x8 wf[4][4];
#pragma unroll
    for (int gt = 0; gt < 4; gt++)
#pragma unroll
        for (int s = 0; s < 4; s++)
            wf[gt][s] = *(const bf16x8*)(LW + (size_t)((((w * 4 + gt) * 4 + s) * 16 + l16) * 4 + hq) * 8);

    for (int i = tid; i < 16 * 136; i += 512) hbuf[0][i] = __float2bfloat16(0.f);
    float c[4] = {0.f, 0.f, 0.f, 0.f};

    const bf16* gp[4];
#pragma unroll
    for (int gt = 0; gt < 4; gt++)
        gp[gt] = G + (size_t)(b0 + l16) * TT * G4 + gt * 128 + w * 16 + hq * 4;
    bf16x4 gx[4];
#pragma unroll
    for (int gt = 0; gt < 4; gt++) gx[gt] = *(const bf16x4*)gp[gt];

    bool hasY = (Y != nullptr);
    bf16* yp = hasY ? (Y + (size_t)(b0 + l16) * TT * HD + w * 16 + hq * 4) : nullptr;
    int hbase = l16 * 136;
    int hcolb = w * 16 + hq * 4;
    __syncthreads();

    for (int t = 0; t < TT; ++t) {
        int rb = t & 1;
        bf16x4 gc[4];
#pragma unroll
        for (int gt = 0; gt < 4; gt++) gc[gt] = gx[gt];
        int tn = (t + 1 < TT) ? t + 1 : t;
#pragma unroll
        for (int gt = 0; gt < 4; gt++) gx[gt] = *(const bf16x4*)(gp[gt] + (size_t)tn * G4);

        bf16x8 hb[4];
#pragma unroll
        for (int s = 0; s < 4; s++)
            hb[s] = *(const bf16x8*)&hbuf[rb][hbase + s * 32 + hq * 8];

        f32x4 acc[4];
#pragma unroll
        for (int gt = 0; gt < 4; gt++) acc[gt] = (f32x4){0.f, 0.f, 0.f, 0.f};
#pragma unroll
        for (int s = 0; s < 4; s++) {
#pragma unroll
            for (int gt = 0; gt < 4; gt++)
                acc[gt] = __builtin_amdgcn_mfma_f32_16x16x32_bf16(wf[gt][s], hb[s], acc[gt], 0, 0, 0);
        }

        float hv[4];
#pragma unroll
        for (int r = 0; r < 4; r++) {
            float xi = acc[0][r] + bs2f(gc[0][r]);
            float xf = acc[1][r] + bs2f(gc[1][r]);
            float xg = acc[2][r] + bs2f(gc[2][r]);
            float xo = acc[3][r] + bs2f(gc[3][r]);
            float iv = fsig(xi), fv = fsig(xf), gv = ftanh(xg), ov = fsig(xo);
            c[r] = fv * c[r] + iv * gv;
            hv[r] = ov * ftanh(c[r]);
        }
        bf16x4 hp;
        hp[0] = f2bs(hv[0]); hp[1] = f2bs(hv[1]); hp[2] = f2bs(hv[2]); hp[3] = f2bs(hv[3]);
        *(bf16x4*)&hbuf[rb ^ 1][hbase + hcolb] = hp;
        if (hasY) *(bf16x4*)(yp + (size_t)t * HD) = hp;
        if (t == TT - 1) {
            float4 hn;
            hn.x = hv[0]; hn.y = hv[1]; hn.z = hv[2]; hn.w = hv[3];
            *(float4*)&HN[(size_t)(b0 + l16) * 256 + hoff + hcolb] = hn;
        }
        __syncthreads();
    }
}

// ---------------- small helpers ----------------
__global__ void bias_sum(const float* a, const float* b, float* o, int n)
{
    int i = blockIdx.x * 256 + threadIdx.x;
    if (i < n) o[i] = a[i] + b[i];
}

__global__ __launch_bounds__(256)
void attn_logits(const float* __restrict__ T1,  // [BC*OC,64]
                 const float* __restrict__ HB,  // [BC,64] (chunk base, includes attn1_b)
                 const float* __restrict__ a2w, // [64]
                 const float* __restrict__ a2b, // [1]
                 float* __restrict__ LG)        // [BC*OC]
{
    int tid = threadIdx.x;
    int lane = tid & 63;
    int wid = tid >> 6;
    int m = blockIdx.x * 4 + wid;
    int b = m / OC;
    float v = T1[(size_t)m * ANF + lane] + HB[b * ANF + lane];
    v = ftanh(v) * a2w[lane];
#pragma unroll
    for (int off = 32; off > 0; off >>= 1) v += __shfl_down(v, off, 64);
    if (lane == 0) LG[m] = v + a2b[0];
}

__global__ __launch_bounds__(128)
void softmax100(const float* __restrict__ LG, float* __restrict__ ATT)
{
    __shared__ float red[128];
    int b = blockIdx.x, c = threadIdx.x;
    float v = (c < OC) ? LG[b * OC + c] : -1e30f;
    red[c] = v; __syncthreads();
    for (int s = 64; s > 0; s >>= 1) { if (c < s) red[c] = fmaxf(red[c], red[c + s]); __syncthreads(); }
    float mx = red[0]; __syncthreads();
    float e = (c < OC) ? __expf(v - mx) : 0.f;
    red[c] = e; __syncthreads();
    for (int s = 64; s > 0; s >>= 1) { if (c < s) red[c] += red[c + s]; __syncthreads(); }
    float inv = 1.f / red[0];
    if (c < OC) ATT[b * OC + c] = e * inv;
}

__global__ __launch_bounds__(256)
void ctx_concat(const bf16* __restrict__ XD,   // [BC,100,3364]
                const float* __restrict__ ATT, // [BC,100]
                const float* __restrict__ HN,  // [BC,256] (chunk base)
                bf16* __restrict__ M)          // [BC,3620] bf16 (chunk base)
{
    __shared__ float al[OC];
    int b = blockIdx.x;
    int tid = threadIdx.x;
    if (tid < OC) al[tid] = ATT[b * OC + tid];
    __syncthreads();
    int s = blockIdx.y * 256 + tid;
    if (s < SS) {
        const bf16* xp = XD + (size_t)b * OC * SS + s;
        float acc = 0.f;
#pragma unroll 4
        for (int c = 0; c < OC; c++) acc = fmaf(__bfloat162float(xp[(size_t)c * SS]), al[c], acc);
        M[(size_t)b * FF + s] = __float2bfloat16(acc);
    } else if (s < FF) {
        M[(size_t)b * FF + s] = __float2bfloat16(HN[b * 256 + (s - SS)]);
    }
}

__global__ __launch_bounds__(256)
void fc2_kernel(const float* __restrict__ H1, // [128,1810]
                const float* __restrict__ w,  // [1810]
                const float* __restrict__ bias,
                float* __restrict__ out)      // [128]
{
    int tid = threadIdx.x;
    int lane = tid & 63, wid = tid >> 6;
    int b = blockIdx.x * 4 + wid;
    float acc = 0.f;
    for (int j = lane; j < HIDN; j += 64) acc = fmaf(H1[(size_t)b * HIDN + j], w[j], acc);
#pragma unroll
    for (int off = 32; off > 0; off >>= 1) acc += __shfl_down(acc, off, 64);
    if (lane == 0) out[b] = acc + bias[0];
}

extern "C" void kernel_launch(void* const* d_in, const int* in_sizes, int n_in,
                              void* d_out, int out_size, void* d_ws, size_t ws_size,
                              hipStream_t stream)
{
    const float* x1   = (const float*)d_in[0];
    const float* x2   = (const float*)d_in[1];
    const float* c1w  = (const float*)d_in[2];
    const float* c1b  = (const float*)d_in[3];
    const float* c2aw = (const float*)d_in[4];
    const float* c2ab = (const float*)d_in[5];
    const float* c2bw = (const float*)d_in[6];
    const float* c2bb = (const float*)d_in[7];
    const float* wih0 = (const float*)d_in[8];
    const float* whh0 = (const float*)d_in[9];
    const float* bih0 = (const float*)d_in[10];
    const float* bhh0 = (const float*)d_in[11];
    const float* wih1 = (const float*)d_in[12];
    const float* whh1 = (const float*)d_in[13];
    const float* bih1 = (const float*)d_in[14];
    const float* bhh1 = (const float*)d_in[15];
    const float* a1w  = (const float*)d_in[16];
    const float* a1b  = (const float*)d_in[17];
    const float* a2w  = (const float*)d_in[18];
    const float* a2b  = (const float*)d_in[19];
    const float* f1w  = (const float*)d_in[20];
    const float* f1b  = (const float*)d_in[21];
    const float* f2w  = (const float*)d_in[22];
    const float* f2b  = (const float*)d_in[23];
    float* out = (float*)d_out;

    // ---- workspace layout (arena with phase overlays; offsets 256B aligned) ----
    char* base = (char*)d_ws;
    bf16* G0    = (bf16*)(base + 0);            // 33,554,432
    bf16* Y0    = (bf16*)(base + 33554432);     //  8,388,608
    bf16* G1    = G0;                           // reuse
    bf16* X2B   = (bf16*)(base + 41943040);     //  4,194,304
    bf16* WIH0B = (bf16*)(base + 46137344);     //     65,536
    bf16* WIH1B = (bf16*)(base + 46202880);     //    131,072
    bf16* LW0   = (bf16*)(base + 46333952);     //    131,072 (packed Whh0, LSTM phase only)
    bf16* LW1   = (bf16*)(base + 46465024);     //    131,072 (end 46,596,096 < 47,641,600)
    bf16* A1c = (bf16*)(base + 0);              // 24,601,600 (CNN phase)
    bf16* A2c = (bf16*)(base + 24601600);       // 23,040,000
    bf16* XDc = A1c;
    bf16* F1WB = (bf16*)(base + 0);             // 13,104,400 (FC1 phase)
    size_t p = 47641600;
    float* BS0  = (float*)(base + p); p += 2048;
    float* BS1  = (float*)(base + p); p += 2048;
    float* HN   = (float*)(base + p); p += 131072;   // 128*256*4
    float* HB   = (float*)(base + p); p += 32768;    // 128*64*4
    float* T1c  = (float*)(base + p); p += 819200;   // 32*100*64*4
    float* LGc  = (float*)(base + p); p += 12800;
    float* ATTc = (float*)(base + p); p += 12800;
    bf16*  MBb  = (bf16*)(base + p); p += 926720;    // 128*3620*2
    float* H1   = (float*)(base + p); p += 926720;   // 128*1810*4
    bf16* WTa   = (bf16*)(base + p); p += 258048;
    bf16* WTb   = (bf16*)(base + p); p += 258048;
    bf16* A1WB  = (bf16*)(base + p); p += 463360;    // 64*3620*2
    if (ws_size < p) {
        zero_kernel<<<1, 128, 0, stream>>>(out, out_size);
        return;
    }

    // ---- weight conversions / repacks ----
    wt_repack<<<504, 256, 0, stream>>>(c2aw, WTa);
    wt_repack<<<504, 256, 0, stream>>>(c2bw, WTb);
    whh_repack<<<32, 256, 0, stream>>>(whh0, LW0);
    whh_repack<<<32, 256, 0, stream>>>(whh1, LW1);
    cvt4_bf16<<<2048, 256, 0, stream>>>(x2,   X2B,   524288);
    cvt4_bf16<<<32,   256, 0, stream>>>(wih0, WIH0B, 8192);
    cvt4_bf16<<<64,   256, 0, stream>>>(wih1, WIH1B, 16384);
    cvt4_bf16<<<227,  256, 0, stream>>>(a1w,  A1WB,  57920);
    bias_sum<<<2, 256, 0, stream>>>(bih0, bhh0, BS0, G4);
    bias_sum<<<2, 256, 0, stream>>>(bih1, bhh1, BS1, G4);

    // ---- LSTM branch (full batch) ----
    gemm_mfma<bf16, 0><<<dim3(512, 8), 256, 0, stream>>>(
        X2B, IDIM, WIH0B, IDIM, BS0, G0, G4, BB * TT, G4, IDIM);
    lstm_mfma<<<BB / 16, 512, 0, stream>>>(G0, LW0, Y0, HN, 0);
    gemm_mfma<bf16, 0><<<dim3(512, 8), 256, 0, stream>>>(
        Y0, HD, WIH1B, HD, BS1, G1, G4, BB * TT, G4, HD);
    lstm_mfma<<<BB / 16, 512, 0, stream>>>(G1, LW1, (bf16*)nullptr, HN, HD);

    // hn-part of attention layer 1 (full batch, once; tiny fp32)
    gemm_tn<float, float, 32, 32, 16, 2, 2, 0><<<dim3(4, 2), 256, 0, stream>>>(
        HN, 256, a1w + SS, FF, a1b, HB, ANF, BB, ANF, 256);

    // ---- CNN branch + attention + ctx, chunked over batch ----
    for (int c0 = 0; c0 < BB; c0 += BC) {
        conv1_kernel<<<dim3(BC, 16), 256, 0, stream>>>(
            x1 + (size_t)c0 * 3 * 64 * 64, c1w, c1b, A1c);
        conv2_mfma<<<dim3(BC, 15), 256, 0, stream>>>(A1c, WTa, c2ab, A2c, W1, W2);
        conv2_mfma<<<dim3(BC, 15), 256, 0, stream>>>(A2c, WTb, c2bb, XDc, W2, W3);
        gemm_mfma<float, 0><<<dim3(50, 1), 256, 0, stream>>>(
            XDc, SS, A1WB, FF, nullptr, T1c, ANF, BC * OC, ANF, SS);
        attn_logits<<<BC * OC / 4, 256, 0, stream>>>(T1c, HB + (size_t)c0 * ANF, a2w, a2b, LGc);
        softmax100<<<BC, 128, 0, stream>>>(LGc, ATTc);
        ctx_concat<<<dim3(BC, 15), 256, 0, stream>>>(
            XDc, ATTc, HN + (size_t)c0 * 256, MBb + (size_t)c0 * FF);
    }

    // ---- fusion MLP ----
    cvt4_bf16<<<6399, 256, 0, stream>>>(f1w, F1WB, 1638050);
    gemm_mfma<float, 1><<<dim3(2, 29), 256, 0, stream>>>(
        MBb, FF, F1WB, FF, f1b, H1, HIDN, BB, HIDN, FF);
    fc2_kernel<<<BB / 4, 256, 0, stream>>>(H1, f2w, f2b, out);
}

// Round 7
// 2041.414 us; speedup vs baseline: 1.1364x; 1.1364x over previous
//
#include <hip/hip_runtime.h>
#include <hip/hip_bf16.h>
#include <math.h>

#define BB 128
#define TT 256
#define IDIM 64
#define HD 128
#define G4 512
#define OC 100
#define W1 62
#define W2 60
#define W3 58
#define NPX1 (W1*W1)
#define NPX2 (W2*W2)
#define NPX3 (W3*W3)
#define SS NPX3
#define FF (SS + 2*HD)
#define HIDN 1810
#define ANF 64
#define BC 32            // batch chunk for CNN branch

typedef __hip_bfloat16 bf16;
typedef __attribute__((ext_vector_type(8))) short bf16x8;
typedef __attribute__((ext_vector_type(4))) short bf16x4;
typedef __attribute__((ext_vector_type(4))) float f32x4;

__device__ __forceinline__ float ldf(const float* p) { return *p; }
__device__ __forceinline__ float ldf(const bf16* p)  { return __bfloat162float(*p); }
__device__ __forceinline__ void  stf(float* p, float v) { *p = v; }
__device__ __forceinline__ void  stf(bf16* p, float v)  { *p = __float2bfloat16(v); }

__device__ __forceinline__ short f2bs(float v) {
    bf16 t = __float2bfloat16(v); short s; __builtin_memcpy(&s, &t, 2); return s;
}
__device__ __forceinline__ float bs2f(short s) {
    unsigned u = ((unsigned)(unsigned short)s) << 16;
    float f; __builtin_memcpy(&f, &u, 4); return f;
}
__device__ __forceinline__ float fsig(float x) {
    return __builtin_amdgcn_rcpf(1.f + __expf(-x));
}
__device__ __forceinline__ float ftanh(float x) {
    float t = __expf(-2.f * fabsf(x));
    float r = __builtin_amdgcn_rcpf(1.f + t);
    float m = 1.f - 2.f * t * r;
    return copysignf(m, x);
}

__global__ void zero_kernel(float* o, int n)
{
    int i = blockIdx.x * 256 + threadIdx.x;
    if (i < n) o[i] = 0.f;
}

// ---------------- fp32 -> bf16 vectorized convert ----------------
__global__ __launch_bounds__(256)
void cvt4_bf16(const float* __restrict__ s, bf16* __restrict__ d, int n4)
{
    int i = blockIdx.x * 256 + threadIdx.x;
    if (i >= n4) return;
    float4 v = ((const float4*)s)[i];
    bf16x4 o;
    o[0] = f2bs(v.x); o[1] = f2bs(v.y); o[2] = f2bs(v.z); o[3] = f2bs(v.w);
    *(bf16x4*)(d + 4 * (size_t)i) = o;
}

// ---------------- conv1: [BC,3,64,64] -> relu -> [BC,100,62,62] (bf16 out) ----------------
__global__ __launch_bounds__(256)
void conv1_kernel(const float* __restrict__ x1,
                  const float* __restrict__ w,     // [100,3,3,3]
                  const float* __restrict__ bias,  // [100]
                  bf16* __restrict__ out)          // [BC,100,62,62]
{
    __shared__ float wl[2700];
    __shared__ float bl[OC];
    int tid = threadIdx.x;
    for (int i = tid; i < 2700; i += 256) wl[i] = w[i];
    if (tid < OC) bl[tid] = bias[tid];
    __syncthreads();
    int b  = blockIdx.x;
    int px = blockIdx.y * 256 + tid;
    if (px >= NPX1) return;
    int y = px / W1, x = px % W1;
    float in[3][3][3];
    const float* xb = x1 + (size_t)b * 3 * 64 * 64;
#pragma unroll
    for (int ic = 0; ic < 3; ic++)
#pragma unroll
        for (int r = 0; r < 3; r++)
#pragma unroll
            for (int c = 0; c < 3; c++)
                in[ic][r][c] = xb[(ic * 64 + y + r) * 64 + x + c];
    bf16* ob = out + (size_t)b * OC * NPX1 + px;
    for (int oc = 0; oc < OC; ++oc) {
        float acc = bl[oc];
        const float* wp = &wl[oc * 27];
#pragma unroll
        for (int ic = 0; ic < 3; ic++)
#pragma unroll
            for (int r = 0; r < 3; r++)
#pragma unroll
                for (int c = 0; c < 3; c++)
                    acc = fmaf(in[ic][r][c], wp[ic * 9 + r * 3 + c], acc);
        ob[(size_t)oc * NPX1] = __float2bfloat16(fmaxf(acc, 0.f));
    }
}

// ---------------- conv2 weight repack: fp32 [oc][ic][3][3] -> bf16 WT[t][s][oc112][i32] ----------------
__global__ __launch_bounds__(256)
void wt_repack(const float* __restrict__ w, bf16* __restrict__ WT)
{
    int idx = blockIdx.x * 256 + threadIdx.x;   // over 9*4*112*32 = 129024
    if (idx >= 129024) return;
    int i  = idx & 31;
    int oc = (idx >> 5) % 112;
    int ts = idx / (112 * 32);   // t*4+s
    int s = ts & 3, t = ts >> 2;
    int ic = s * 32 + i;
    float v = 0.f;
    if (oc < OC && ic < OC) v = w[(oc * OC + ic) * 9 + t];
    WT[idx] = __float2bfloat16(v);
}

// ---------------- Whh repack: fp32 [512,128] -> bf16 LW in A-fragment order ----------------
// group idx: hq(2b) | l16(4b) | s(2b) | gt(2b) | w(3b); 8 bf16 per group.
__global__ __launch_bounds__(256)
void whh_repack(const float* __restrict__ Whh, bf16* __restrict__ LW)
{
    int idx = blockIdx.x * 256 + threadIdx.x;   // 8192 groups
    if (idx >= 8192) return;
    int hq  = idx & 3;
    int l16 = (idx >> 2) & 15;
    int s   = (idx >> 6) & 3;
    int gt  = (idx >> 8) & 3;
    int w   = idx >> 10;
    const float* src = Whh + (size_t)(gt * 128 + w * 16 + l16) * 128 + s * 32 + hq * 8;
    float4 v0 = *(const float4*)src;
    float4 v1 = *(const float4*)(src + 4);
    bf16x8 f;
    f[0] = f2bs(v0.x); f[1] = f2bs(v0.y); f[2] = f2bs(v0.z); f[3] = f2bs(v0.w);
    f[4] = f2bs(v1.x); f[5] = f2bs(v1.y); f[6] = f2bs(v1.z); f[7] = f2bs(v1.w);
    *(bf16x8*)(LW + (size_t)idx * 8) = f;
}

// ---------------- conv2 via MFMA implicit GEMM (ic-contiguous LDS) ----------------
__global__ __launch_bounds__(256, 2)
void conv2_mfma(const bf16* __restrict__ in,   // [BC,100,iw,iw]
                const bf16* __restrict__ WT,   // [9][4][112][32] bf16
                const float* __restrict__ bias,
                bf16* __restrict__ out,        // [BC,100,ow,ow]
                int iw, int ow)
{
    __shared__ bf16 il[6 * 72 * 40];           // [r][x(72)][ic(pad 40)]
    int tid = threadIdx.x;
    int b = blockIdx.x;
    int y0 = blockIdx.y * 4;
    int wid = tid >> 6;
    int l = tid & 63;
    int hq = l >> 4;
    int l16 = l & 15;
    int yo = y0 + wid;

    f32x4 acc[7][4];
#pragma unroll
    for (int f = 0; f < 7; f++) {
#pragma unroll
        for (int r = 0; r < 4; r++) {
            int oc = f * 16 + hq * 4 + r;
            float bv = (oc < OC) ? bias[oc] : 0.f;
#pragma unroll
            for (int n = 0; n < 4; n++) acc[f][n][r] = bv;
        }
    }

    const size_t ims = (size_t)iw * iw;
    int icl = tid & 31;
    int t2  = tid >> 5;                        // 0..7
    for (int s = 0; s < 4; ++s) {
        __syncthreads();
        int ic = s * 32 + icl;
        bool icok = ic < OC;
        const bf16* ibase = in + (size_t)(b * OC + ic) * ims;
#pragma unroll
        for (int it = 0; it < 7; ++it) {
            int u2 = t2 + it * 8;              // 0..53 over (r:6, xb:9)
            if (u2 < 54) {
                int r = u2 / 9, xb = u2 - r * 9;
                int x8 = xb * 8;
                int yy = y0 + r;
                bf16x8 v = {0, 0, 0, 0, 0, 0, 0, 0};
                if (icok && yy < iw && x8 < iw) {
                    const short* sp = (const short*)(ibase + (size_t)yy * iw + x8);
                    if (x8 + 8 <= iw) {
                        const unsigned* sp32 = (const unsigned*)sp;
#pragma unroll
                        for (int q = 0; q < 4; q++)
                            ((unsigned*)&v)[q] = sp32[q];
                    } else {
                        for (int k = 0; k < 8; k++)
                            if (x8 + k < iw) ((short*)&v)[k] = sp[k];
                    }
                }
                bf16* dst = &il[(r * 72 + x8) * 40 + icl];
#pragma unroll
                for (int k = 0; k < 8; k++)
                    *(short*)&dst[k * 40] = ((short*)&v)[k];
            }
        }
        __syncthreads();

        const bf16* wts = WT + (size_t)s * 112 * 32;
#pragma unroll
        for (int ky = 0; ky < 3; ++ky) {
#pragma unroll
            for (int kx = 0; kx < 3; ++kx) {
                int t = ky * 3 + kx;
                uint4 a[7];
                const uint4* wp = (const uint4*)(wts + (size_t)t * 4 * 112 * 32);
#pragma unroll
                for (int f = 0; f < 7; f++)
                    a[f] = wp[(f * 16 + l16) * 4 + hq];
                bf16x8 bfr[4];
#pragma unroll
                for (int n = 0; n < 4; n++)
                    bfr[n] = *(const bf16x8*)&il[((wid + ky) * 72 + kx + l16 + n * 16) * 40 + hq * 8];
#pragma unroll
                for (int f = 0; f < 7; f++)
#pragma unroll
                    for (int n = 0; n < 4; n++)
                        acc[f][n] = __builtin_amdgcn_mfma_f32_16x16x32_bf16(
                            *(const bf16x8*)&a[f], bfr[n], acc[f][n], 0, 0, 0);
            }
        }
    }

    if (yo < ow) {
#pragma unroll
        for (int f = 0; f < 7; f++) {
#pragma unroll
            for (int r = 0; r < 4; r++) {
                int oc = f * 16 + hq * 4 + r;
                if (oc < OC) {
#pragma unroll
                    for (int n = 0; n < 4; n++) {
                        int x = n * 16 + l16;
                        if (x < ow)
                            out[((size_t)(b * OC + oc) * ow + yo) * ow + x] =
                                __float2bfloat16(fmaxf(acc[f][n][r], 0.f));
                    }
                }
            }
        }
    }
}

// ---------------- generic bf16 MFMA GEMM: C[M,N] = A[M,K] @ B[N,K]^T (+bias, +relu) ----------------
template<typename TC, int ACT>
__global__ __launch_bounds__(256)
void gemm_mfma(const bf16* __restrict__ A, int lda,
               const bf16* __restrict__ B, int ldb,
               const float* __restrict__ bias,
               TC* __restrict__ C, int ldc,
               int M, int N, int K)
{
    __shared__ bf16 As[64 * 72];
    __shared__ bf16 Bs[64 * 72];
    int tid = threadIdx.x;
    int l = tid & 63, wid = tid >> 6;
    int l16 = l & 15, h = l >> 4;
    int m0 = blockIdx.x * 64, n0 = blockIdx.y * 64;
    f32x4 acc[4];
#pragma unroll
    for (int nb = 0; nb < 4; nb++) acc[nb] = (f32x4){0.f, 0.f, 0.f, 0.f};

    int rs = tid >> 3;             // 0..31 staging row
    int kc = (tid & 7) * 8;        // 0..56 staging k-col

    for (int k0 = 0; k0 < K; k0 += 64) {
        int kr = K - k0;
#pragma unroll
        for (int half = 0; half < 2; half++) {
            int rr = rs + half * 32;
            bf16x8 av = {0, 0, 0, 0, 0, 0, 0, 0};
            int m = m0 + rr;
            if (m < M) {
                const short* src = (const short*)(A + (size_t)m * lda + k0 + kc);
                if (kc + 8 <= kr) av = *(const bf16x8*)src;
                else if (kc < kr) {
                    for (int j = 0; j < 8; j++) if (kc + j < kr) ((short*)&av)[j] = src[j];
                }
            }
            *(bf16x8*)&As[rr * 72 + kc] = av;
            bf16x8 bv = {0, 0, 0, 0, 0, 0, 0, 0};
            int n = n0 + rr;
            if (n < N) {
                const short* src = (const short*)(B + (size_t)n * ldb + k0 + kc);
                if (kc + 8 <= kr) bv = *(const bf16x8*)src;
                else if (kc < kr) {
                    for (int j = 0; j < 8; j++) if (kc + j < kr) ((short*)&bv)[j] = src[j];
                }
            }
            *(bf16x8*)&Bs[rr * 72 + kc] = bv;
        }
        __syncthreads();
#pragma unroll
        for (int kk = 0; kk < 2; kk++) {
            bf16x8 af = *(const bf16x8*)&As[(wid * 16 + l16) * 72 + kk * 32 + h * 8];
#pragma unroll
            for (int nb = 0; nb < 4; nb++) {
                bf16x8 bfr = *(const bf16x8*)&Bs[(nb * 16 + l16) * 72 + kk * 32 + h * 8];
                acc[nb] = __builtin_amdgcn_mfma_f32_16x16x32_bf16(af, bfr, acc[nb], 0, 0, 0);
            }
        }
        __syncthreads();
    }
#pragma unroll
    for (int nb = 0; nb < 4; nb++) {
        int col = n0 + nb * 16 + l16;
        if (col >= N) continue;
        float bv = bias ? bias[col] : 0.f;
#pragma unroll
        for (int reg = 0; reg < 4; reg++) {
            int row = m0 + wid * 16 + h * 4 + reg;
            if (row < M) {
                float v = acc[nb][reg] + bv;
                if (ACT == 1) v = fmaxf(v, 0.f);
                stf(&C[(size_t)row * ldc + col], v);
            }
        }
    }
}

// ---------------- small fp32 GEMM (kept for tiny HB matmul) ----------------
template<typename TA, typename TC, int BM, int BN, int BK, int TM, int TN, int ACT>
__global__ __launch_bounds__((BM / TM) * (BN / TN))
void gemm_tn(const TA* __restrict__ A, int lda,
             const float* __restrict__ Bmat, int ldb,
             const float* __restrict__ bias,
             TC* __restrict__ C, int ldc,
             int M, int N, int K)
{
    constexpr int TX = BN / TN;
    constexpr int TY = BM / TM;
    constexpr int NT = TX * TY;
    __shared__ float As[BK][BM + 1];
    __shared__ float Bs[BK][BN + 1];
    int tid = threadIdx.x;
    int tx = tid % TX, ty = tid / TX;
    int m0 = blockIdx.x * BM, n0 = blockIdx.y * BN;
    float acc[TM][TN] = {};
    for (int k0 = 0; k0 < K; k0 += BK) {
        for (int idx = tid; idx < BM * BK; idx += NT) {
            int i = idx / BK, j = idx % BK;
            int m = m0 + i, k = k0 + j;
            As[j][i] = (m < M && k < K) ? ldf(&A[(size_t)m * lda + k]) : 0.f;
        }
        for (int idx = tid; idx < BN * BK; idx += NT) {
            int i = idx / BK, j = idx % BK;
            int n = n0 + i, k = k0 + j;
            Bs[j][i] = (n < N && k < K) ? Bmat[(size_t)n * ldb + k] : 0.f;
        }
        __syncthreads();
#pragma unroll
        for (int k = 0; k < BK; ++k) {
            float av[TM], bv[TN];
#pragma unroll
            for (int i = 0; i < TM; i++) av[i] = As[k][ty * TM + i];
#pragma unroll
            for (int j = 0; j < TN; j++) bv[j] = Bs[k][tx * TN + j];
#pragma unroll
            for (int i = 0; i < TM; i++)
#pragma unroll
                for (int j = 0; j < TN; j++)
                    acc[i][j] += av[i] * bv[j];
        }
        __syncthreads();
    }
#pragma unroll
    for (int i = 0; i < TM; i++) {
        int m = m0 + ty * TM + i;
        if (m >= M) continue;
#pragma unroll
        for (int j = 0; j < TN; j++) {
            int n = n0 + tx * TN + j;
            if (n >= N) continue;
            float v = acc[i][j] + (bias ? bias[n] : 0.f);
            if (ACT == 1) v = fmaxf(v, 0.f);
            stf(&C[(size_t)m * ldc + n], v);
        }
    }
}

// ---------------- LSTM recurrence via MFMA, weights pinned in VGPRs ----------------
// 8 blocks x 512 thr; wave w owns gate-cols [16w,16w+16) of each gate tile.
// Double-buffered h in LDS -> single barrier per step.
__global__ __launch_bounds__(512, 1)
void lstm_mfma(const bf16* __restrict__ G,   // [B,T,512] x-part + biases
               const bf16* __restrict__ LW,  // packed Whh fragments
               bf16* __restrict__ Y,         // [B,T,128] or nullptr
               float* __restrict__ HN,       // [B,256]
               int hoff)
{
    __shared__ bf16 hbuf[2][16 * 136];
    int tid = threadIdx.x;
    int w = tid >> 6, l = tid & 63;
    int l16 = l & 15, hq = l >> 4;
    int b0 = blockIdx.x * 16;

    // A-fragments of Whh: 16 x b128 loads from the packed layout.
    bf16x8 wf[4][4];
#pragma unroll
    for (int gt = 0; gt < 4; gt++)
#pragma unroll
        for (int s = 0; s < 4; s++)
            wf[gt][s] = *(const bf16x8*)(LW + (size_t)((((w * 4 + gt) * 4 + s) * 16 + l16) * 4 + hq) * 8);
    // PIN: mark each fragment as asm-modified so the rematerializer cannot
    // legally re-load it from memory inside the t-loop (r5/r6 showed hipcc
    // sinking these 16 loop-invariant loads into the loop: VGPR 60-72,
    // 63-73 GB/s of weight re-reads, 1.4% VALUBusy).
#pragma unroll
    for (int gt = 0; gt < 4; gt++)
#pragma unroll
        for (int s = 0; s < 4; s++)
            asm volatile("" : "+v"(wf[gt][s]));

    for (int i = tid; i < 16 * 136; i += 512) hbuf[0][i] = __float2bfloat16(0.f);
    float c[4] = {0.f, 0.f, 0.f, 0.f};

    const bf16* gp[4];
#pragma unroll
    for (int gt = 0; gt < 4; gt++)
        gp[gt] = G + (size_t)(b0 + l16) * TT * G4 + gt * 128 + w * 16 + hq * 4;
    bf16x4 gx[4];
#pragma unroll
    for (int gt = 0; gt < 4; gt++) gx[gt] = *(const bf16x4*)gp[gt];

    bool hasY = (Y != nullptr);
    bf16* yp = hasY ? (Y + (size_t)(b0 + l16) * TT * HD + w * 16 + hq * 4) : nullptr;
    int hbase = l16 * 136;
    int hcolb = w * 16 + hq * 4;
    __syncthreads();

    for (int t = 0; t < TT; ++t) {
        int rb = t & 1;
        bf16x4 gc[4];
#pragma unroll
        for (int gt = 0; gt < 4; gt++) gc[gt] = gx[gt];
        int tn = (t + 1 < TT) ? t + 1 : t;
#pragma unroll
        for (int gt = 0; gt < 4; gt++) gx[gt] = *(const bf16x4*)(gp[gt] + (size_t)tn * G4);

        bf16x8 hb[4];
#pragma unroll
        for (int s = 0; s < 4; s++)
            hb[s] = *(const bf16x8*)&hbuf[rb][hbase + s * 32 + hq * 8];

        f32x4 acc[4];
#pragma unroll
        for (int gt = 0; gt < 4; gt++) acc[gt] = (f32x4){0.f, 0.f, 0.f, 0.f};
#pragma unroll
        for (int s = 0; s < 4; s++) {
#pragma unroll
            for (int gt = 0; gt < 4; gt++)
                acc[gt] = __builtin_amdgcn_mfma_f32_16x16x32_bf16(wf[gt][s], hb[s], acc[gt], 0, 0, 0);
        }

        float hv[4];
#pragma unroll
        for (int r = 0; r < 4; r++) {
            float xi = acc[0][r] + bs2f(gc[0][r]);
            float xf = acc[1][r] + bs2f(gc[1][r]);
            float xg = acc[2][r] + bs2f(gc[2][r]);
            float xo = acc[3][r] + bs2f(gc[3][r]);
            float iv = fsig(xi), fv = fsig(xf), gv = ftanh(xg), ov = fsig(xo);
            c[r] = fv * c[r] + iv * gv;
            hv[r] = ov * ftanh(c[r]);
        }
        bf16x4 hp;
        hp[0] = f2bs(hv[0]); hp[1] = f2bs(hv[1]); hp[2] = f2bs(hv[2]); hp[3] = f2bs(hv[3]);
        *(bf16x4*)&hbuf[rb ^ 1][hbase + hcolb] = hp;
        if (hasY) *(bf16x4*)(yp + (size_t)t * HD) = hp;
        if (t == TT - 1) {
            float4 hn;
            hn.x = hv[0]; hn.y = hv[1]; hn.z = hv[2]; hn.w = hv[3];
            *(float4*)&HN[(size_t)(b0 + l16) * 256 + hoff + hcolb] = hn;
        }
        __syncthreads();
    }
}

// ---------------- small helpers ----------------
__global__ void bias_sum(const float* a, const float* b, float* o, int n)
{
    int i = blockIdx.x * 256 + threadIdx.x;
    if (i < n) o[i] = a[i] + b[i];
}

__global__ __launch_bounds__(256)
void attn_logits(const float* __restrict__ T1,  // [BC*OC,64]
                 const float* __restrict__ HB,  // [BC,64] (chunk base, includes attn1_b)
                 const float* __restrict__ a2w, // [64]
                 const float* __restrict__ a2b, // [1]
                 float* __restrict__ LG)        // [BC*OC]
{
    int tid = threadIdx.x;
    int lane = tid & 63;
    int wid = tid >> 6;
    int m = blockIdx.x * 4 + wid;
    int b = m / OC;
    float v = T1[(size_t)m * ANF + lane] + HB[b * ANF + lane];
    v = ftanh(v) * a2w[lane];
#pragma unroll
    for (int off = 32; off > 0; off >>= 1) v += __shfl_down(v, off, 64);
    if (lane == 0) LG[m] = v + a2b[0];
}

__global__ __launch_bounds__(128)
void softmax100(const float* __restrict__ LG, float* __restrict__ ATT)
{
    __shared__ float red[128];
    int b = blockIdx.x, c = threadIdx.x;
    float v = (c < OC) ? LG[b * OC + c] : -1e30f;
    red[c] = v; __syncthreads();
    for (int s = 64; s > 0; s >>= 1) { if (c < s) red[c] = fmaxf(red[c], red[c + s]); __syncthreads(); }
    float mx = red[0]; __syncthreads();
    float e = (c < OC) ? __expf(v - mx) : 0.f;
    red[c] = e; __syncthreads();
    for (int s = 64; s > 0; s >>= 1) { if (c < s) red[c] += red[c + s]; __syncthreads(); }
    float inv = 1.f / red[0];
    if (c < OC) ATT[b * OC + c] = e * inv;
}

__global__ __launch_bounds__(256)
void ctx_concat(const bf16* __restrict__ XD,   // [BC,100,3364]
                const float* __restrict__ ATT, // [BC,100]
                const float* __restrict__ HN,  // [BC,256] (chunk base)
                bf16* __restrict__ M)          // [BC,3620] bf16 (chunk base)
{
    __shared__ float al[OC];
    int b = blockIdx.x;
    int tid = threadIdx.x;
    if (tid < OC) al[tid] = ATT[b * OC + tid];
    __syncthreads();
    int s = blockIdx.y * 256 + tid;
    if (s < SS) {
        const bf16* xp = XD + (size_t)b * OC * SS + s;
        float acc = 0.f;
#pragma unroll 4
        for (int c = 0; c < OC; c++) acc = fmaf(__bfloat162float(xp[(size_t)c * SS]), al[c], acc);
        M[(size_t)b * FF + s] = __float2bfloat16(acc);
    } else if (s < FF) {
        M[(size_t)b * FF + s] = __float2bfloat16(HN[b * 256 + (s - SS)]);
    }
}

__global__ __launch_bounds__(256)
void fc2_kernel(const float* __restrict__ H1, // [128,1810]
                const float* __restrict__ w,  // [1810]
                const float* __restrict__ bias,
                float* __restrict__ out)      // [128]
{
    int tid = threadIdx.x;
    int lane = tid & 63, wid = tid >> 6;
    int b = blockIdx.x * 4 + wid;
    float acc = 0.f;
    for (int j = lane; j < HIDN; j += 64) acc = fmaf(H1[(size_t)b * HIDN + j], w[j], acc);
#pragma unroll
    for (int off = 32; off > 0; off >>= 1) acc += __shfl_down(acc, off, 64);
    if (lane == 0) out[b] = acc + bias[0];
}

extern "C" void kernel_launch(void* const* d_in, const int* in_sizes, int n_in,
                              void* d_out, int out_size, void* d_ws, size_t ws_size,
                              hipStream_t stream)
{
    const float* x1   = (const float*)d_in[0];
    const float* x2   = (const float*)d_in[1];
    const float* c1w  = (const float*)d_in[2];
    const float* c1b  = (const float*)d_in[3];
    const float* c2aw = (const float*)d_in[4];
    const float* c2ab = (const float*)d_in[5];
    const float* c2bw = (const float*)d_in[6];
    const float* c2bb = (const float*)d_in[7];
    const float* wih0 = (const float*)d_in[8];
    const float* whh0 = (const float*)d_in[9];
    const float* bih0 = (const float*)d_in[10];
    const float* bhh0 = (const float*)d_in[11];
    const float* wih1 = (const float*)d_in[12];
    const float* whh1 = (const float*)d_in[13];
    const float* bih1 = (const float*)d_in[14];
    const float* bhh1 = (const float*)d_in[15];
    const float* a1w  = (const float*)d_in[16];
    const float* a1b  = (const float*)d_in[17];
    const float* a2w  = (const float*)d_in[18];
    const float* a2b  = (const float*)d_in[19];
    const float* f1w  = (const float*)d_in[20];
    const float* f1b  = (const float*)d_in[21];
    const float* f2w  = (const float*)d_in[22];
    const float* f2b  = (const float*)d_in[23];
    float* out = (float*)d_out;

    // ---- workspace layout (arena with phase overlays; offsets 256B aligned) ----
    char* base = (char*)d_ws;
    bf16* G0    = (bf16*)(base + 0);            // 33,554,432
    bf16* Y0    = (bf16*)(base + 33554432);     //  8,388,608
    bf16* G1    = G0;                           // reuse
    bf16* X2B   = (bf16*)(base + 41943040);     //  4,194,304
    bf16* WIH0B = (bf16*)(base + 46137344);     //     65,536
    bf16* WIH1B = (bf16*)(base + 46202880);     //    131,072
    bf16* LW0   = (bf16*)(base + 46333952);     //    131,072 (packed Whh0, LSTM phase only)
    bf16* LW1   = (bf16*)(base + 46465024);     //    131,072 (end 46,596,096 < 47,641,600)
    bf16* A1c = (bf16*)(base + 0);              // 24,601,600 (CNN phase)
    bf16* A2c = (bf16*)(base + 24601600);       // 23,040,000
    bf16* XDc = A1c;
    bf16* F1WB = (bf16*)(base + 0);             // 13,104,400 (FC1 phase)
    size_t p = 47641600;
    float* BS0  = (float*)(base + p); p += 2048;
    float* BS1  = (float*)(base + p); p += 2048;
    float* HN   = (float*)(base + p); p += 131072;   // 128*256*4
    float* HB   = (float*)(base + p); p += 32768;    // 128*64*4
    float* T1c  = (float*)(base + p); p += 819200;   // 32*100*64*4
    float* LGc  = (float*)(base + p); p += 12800;
    float* ATTc = (float*)(base + p); p += 12800;
    bf16*  MBb  = (bf16*)(base + p); p += 926720;    // 128*3620*2
    float* H1   = (float*)(base + p); p += 926720;   // 128*1810*4
    bf16* WTa   = (bf16*)(base + p); p += 258048;
    bf16* WTb   = (bf16*)(base + p); p += 258048;
    bf16* A1WB  = (bf16*)(base + p); p += 463360;    // 64*3620*2
    if (ws_size < p) {
        zero_kernel<<<1, 128, 0, stream>>>(out, out_size);
        return;
    }

    // ---- weight conversions / repacks ----
    wt_repack<<<504, 256, 0, stream>>>(c2aw, WTa);
    wt_repack<<<504, 256, 0, stream>>>(c2bw, WTb);
    whh_repack<<<32, 256, 0, stream>>>(whh0, LW0);
    whh_repack<<<32, 256, 0, stream>>>(whh1, LW1);
    cvt4_bf16<<<2048, 256, 0, stream>>>(x2,   X2B,   524288);
    cvt4_bf16<<<32,   256, 0, stream>>>(wih0, WIH0B, 8192);
    cvt4_bf16<<<64,   256, 0, stream>>>(wih1, WIH1B, 16384);
    cvt4_bf16<<<227,  256, 0, stream>>>(a1w,  A1WB,  57920);
    bias_sum<<<2, 256, 0, stream>>>(bih0, bhh0, BS0, G4);
    bias_sum<<<2, 256, 0, stream>>>(bih1, bhh1, BS1, G4);

    // ---- LSTM branch (full batch) ----
    gemm_mfma<bf16, 0><<<dim3(512, 8), 256, 0, stream>>>(
        X2B, IDIM, WIH0B, IDIM, BS0, G0, G4, BB * TT, G4, IDIM);
    lstm_mfma<<<BB / 16, 512, 0, stream>>>(G0, LW0, Y0, HN, 0);
    gemm_mfma<bf16, 0><<<dim3(512, 8), 256, 0, stream>>>(
        Y0, HD, WIH1B, HD, BS1, G1, G4, BB * TT, G4, HD);
    lstm_mfma<<<BB / 16, 512, 0, stream>>>(G1, LW1, (bf16*)nullptr, HN, HD);

    // hn-part of attention layer 1 (full batch, once; tiny fp32)
    gemm_tn<float, float, 32, 32, 16, 2, 2, 0><<<dim3(4, 2), 256, 0, stream>>>(
        HN, 256, a1w + SS, FF, a1b, HB, ANF, BB, ANF, 256);

    // ---- CNN branch + attention + ctx, chunked over batch ----
    for (int c0 = 0; c0 < BB; c0 += BC) {
        conv1_kernel<<<dim3(BC, 16), 256, 0, stream>>>(
            x1 + (size_t)c0 * 3 * 64 * 64, c1w, c1b, A1c);
        conv2_mfma<<<dim3(BC, 15), 256, 0, stream>>>(A1c, WTa, c2ab, A2c, W1, W2);
        conv2_mfma<<<dim3(BC, 15), 256, 0, stream>>>(A2c, WTb, c2bb, XDc, W2, W3);
        gemm_mfma<float, 0><<<dim3(50, 1), 256, 0, stream>>>(
            XDc, SS, A1WB, FF, nullptr, T1c, ANF, BC * OC, ANF, SS);
        attn_logits<<<BC * OC / 4, 256, 0, stream>>>(T1c, HB + (size_t)c0 * ANF, a2w, a2b, LGc);
        softmax100<<<BC, 128, 0, stream>>>(LGc, ATTc);
        ctx_concat<<<dim3(BC, 15), 256, 0, stream>>>(
            XDc, ATTc, HN + (size_t)c0 * 256, MBb + (size_t)c0 * FF);
    }

    // ---- fusion MLP ----
    cvt4_bf16<<<6399, 256, 0, stream>>>(f1w, F1WB, 1638050);
    gemm_mfma<float, 1><<<dim3(2, 29), 256, 0, stream>>>(
        MBb, FF, F1WB, FF, f1b, H1, HIDN, BB, HIDN, FF);
    fc2_kernel<<<BB / 4, 256, 0, stream>>>(H1, f2w, f2b, out);
}

// Round 9
// 1606.463 us; speedup vs baseline: 1.4441x; 1.2708x over previous
//
#include <hip/hip_runtime.h>
#include <hip/hip_bf16.h>
#include <math.h>

#define BB 128
#define TT 256
#define IDIM 64
#define HD 128
#define G4 512
#define OC 100
#define W1 62
#define W2 60
#define W3 58
#define NPX1 (W1*W1)
#define NPX2 (W2*W2)
#define NPX3 (W3*W3)
#define SS NPX3
#define FF (SS + 2*HD)
#define HIDN 1810
#define ANF 64
#define BC 32            // batch chunk for CNN branch

typedef __hip_bfloat16 bf16;
typedef __attribute__((ext_vector_type(8))) short bf16x8;
typedef __attribute__((ext_vector_type(4))) short bf16x4;
typedef __attribute__((ext_vector_type(4))) float f32x4;

__device__ __forceinline__ float ldf(const float* p) { return *p; }
__device__ __forceinline__ float ldf(const bf16* p)  { return __bfloat162float(*p); }
__device__ __forceinline__ void  stf(float* p, float v) { *p = v; }
__device__ __forceinline__ void  stf(bf16* p, float v)  { *p = __float2bfloat16(v); }

__device__ __forceinline__ short f2bs(float v) {
    bf16 t = __float2bfloat16(v); short s; __builtin_memcpy(&s, &t, 2); return s;
}
__device__ __forceinline__ float ubl(unsigned u) {   // low bf16 of packed pair -> f32
    unsigned x = u << 16; float f; __builtin_memcpy(&f, &x, 4); return f;
}
__device__ __forceinline__ float ubh(unsigned u) {   // high bf16 of packed pair -> f32
    unsigned x = u & 0xFFFF0000u; float f; __builtin_memcpy(&f, &x, 4); return f;
}
__device__ __forceinline__ float fsig(float x) {
    return __builtin_amdgcn_rcpf(1.f + __expf(-x));
}
__device__ __forceinline__ float ftanh(float x) {
    float t = __expf(-2.f * fabsf(x));
    float r = __builtin_amdgcn_rcpf(1.f + t);
    float m = 1.f - 2.f * t * r;
    return copysignf(m, x);
}

__device__ __forceinline__ bf16x8 load8(const bf16* p) { return *(const bf16x8*)p; }
__device__ __forceinline__ bf16x8 load8(const float* p) {
    float4 x = *(const float4*)p;
    float4 y = *(const float4*)(p + 4);
    bf16x8 r;
    r[0] = f2bs(x.x); r[1] = f2bs(x.y); r[2] = f2bs(x.z); r[3] = f2bs(x.w);
    r[4] = f2bs(y.x); r[5] = f2bs(y.y); r[6] = f2bs(y.z); r[7] = f2bs(y.w);
    return r;
}

__global__ void zero_kernel(float* o, int n)
{
    int i = blockIdx.x * 256 + threadIdx.x;
    if (i < n) o[i] = 0.f;
}

// ---------------- fp32 -> bf16 vectorized convert ----------------
__global__ __launch_bounds__(256)
void cvt4_bf16(const float* __restrict__ s, bf16* __restrict__ d, int n4)
{
    int i = blockIdx.x * 256 + threadIdx.x;
    if (i >= n4) return;
    float4 v = ((const float4*)s)[i];
    bf16x4 o;
    o[0] = f2bs(v.x); o[1] = f2bs(v.y); o[2] = f2bs(v.z); o[3] = f2bs(v.w);
    *(bf16x4*)(d + 4 * (size_t)i) = o;
}

// ---------------- conv1: [BC,3,64,64] -> relu -> [BC,100,62,62] (bf16 out) ----------------
__global__ __launch_bounds__(256)
void conv1_kernel(const float* __restrict__ x1,
                  const float* __restrict__ w,     // [100,3,3,3]
                  const float* __restrict__ bias,  // [100]
                  bf16* __restrict__ out)          // [BC,100,62,62]
{
    __shared__ float wl[2700];
    __shared__ float bl[OC];
    int tid = threadIdx.x;
    for (int i = tid; i < 2700; i += 256) wl[i] = w[i];
    if (tid < OC) bl[tid] = bias[tid];
    __syncthreads();
    int b  = blockIdx.x;
    int px = blockIdx.y * 256 + tid;
    if (px >= NPX1) return;
    int y = px / W1, x = px % W1;
    float in[3][3][3];
    const float* xb = x1 + (size_t)b * 3 * 64 * 64;
#pragma unroll
    for (int ic = 0; ic < 3; ic++)
#pragma unroll
        for (int r = 0; r < 3; r++)
#pragma unroll
            for (int c = 0; c < 3; c++)
                in[ic][r][c] = xb[(ic * 64 + y + r) * 64 + x + c];
    bf16* ob = out + (size_t)b * OC * NPX1 + px;
    for (int oc = 0; oc < OC; ++oc) {
        float acc = bl[oc];
        const float* wp = &wl[oc * 27];
#pragma unroll
        for (int ic = 0; ic < 3; ic++)
#pragma unroll
            for (int r = 0; r < 3; r++)
#pragma unroll
                for (int c = 0; c < 3; c++)
                    acc = fmaf(in[ic][r][c], wp[ic * 9 + r * 3 + c], acc);
        ob[(size_t)oc * NPX1] = __float2bfloat16(fmaxf(acc, 0.f));
    }
}

// ---------------- conv2 weight repack: fp32 [oc][ic][3][3] -> bf16 WT[t][s][oc112][i32] ----------------
__global__ __launch_bounds__(256)
void wt_repack(const float* __restrict__ w, bf16* __restrict__ WT)
{
    int idx = blockIdx.x * 256 + threadIdx.x;   // over 9*4*112*32 = 129024
    if (idx >= 129024) return;
    int i  = idx & 31;
    int oc = (idx >> 5) % 112;
    int ts = idx / (112 * 32);   // t*4+s
    int s = ts & 3, t = ts >> 2;
    int ic = s * 32 + i;
    float v = 0.f;
    if (oc < OC && ic < OC) v = w[(oc * OC + ic) * 9 + t];
    WT[idx] = __float2bfloat16(v);
}

// ---------------- conv2 via MFMA implicit GEMM ----------------
// 512 thr = 8 waves, wave = 1 output row; WT slice staged in LDS (shared by all
// 8 waves -> 8x less L2 weight traffic vs per-wave global A-frag loads).
__global__ __launch_bounds__(512, 1)
void conv2_mfma(const bf16* __restrict__ in,   // [BC,100,iw,iw]
                const bf16* __restrict__ WT,   // [9][4][112][32] bf16
                const float* __restrict__ bias,
                bf16* __restrict__ out,        // [BC,100,ow,ow]
                int iw, int ow)
{
    __shared__ bf16 il[10 * 72 * 40];          // input slice [r][x(72)][ic(pad40)]  57.6 KB
    __shared__ bf16 wl[4032 * 8];              // weights [t][hq][oc] x 8 bf16       64.5 KB
    int tid = threadIdx.x;
    int b = blockIdx.x;
    int y0 = blockIdx.y * 8;
    int wid = tid >> 6;        // 0..7 output row
    int l = tid & 63;
    int hq = l >> 4;
    int l16 = l & 15;
    int yo = y0 + wid;

    f32x4 acc[7][4];
#pragma unroll
    for (int f = 0; f < 7; f++) {
#pragma unroll
        for (int r = 0; r < 4; r++) {
            int oc = f * 16 + hq * 4 + r;
            float bv = (oc < OC) ? bias[oc] : 0.f;
#pragma unroll
            for (int n = 0; n < 4; n++) acc[f][n][r] = bv;
        }
    }

    const size_t ims = (size_t)iw * iw;
    int icl = tid & 31;
    int t2  = tid >> 5;                        // 0..15
    for (int s = 0; s < 4; ++s) {
        __syncthreads();                       // protect il/wl reuse
        // ---- stage input slice (32 ic x 10 rows x 72 cols) ----
        int ic = s * 32 + icl;
        bool icok = ic < OC;
        const bf16* ibase = in + (size_t)(b * OC + ic) * ims;
#pragma unroll
        for (int it = 0; it < 6; ++it) {
            int u2 = t2 + it * 16;             // over (r:10, xb:9) = 90 units
            if (u2 < 90) {
                int r = u2 / 9, xb = u2 - r * 9;
                int x8 = xb * 8;
                int yy = y0 + r;
                bf16x8 v = {0, 0, 0, 0, 0, 0, 0, 0};
                if (icok && yy < iw && x8 < iw) {
                    const short* sp = (const short*)(ibase + (size_t)yy * iw + x8);
                    if (x8 + 8 <= iw) {
                        const unsigned* sp32 = (const unsigned*)sp;
#pragma unroll
                        for (int q = 0; q < 4; q++)
                            ((unsigned*)&v)[q] = sp32[q];
                    } else {
                        for (int k = 0; k < 8; k++)
                            if (x8 + k < iw) ((short*)&v)[k] = sp[k];
                    }
                }
                bf16* dst = &il[(r * 72 + x8) * 40 + icl];
#pragma unroll
                for (int k = 0; k < 8; k++)
                    *(short*)&dst[k * 40] = ((short*)&v)[k];
            }
        }
        // ---- stage WT slice s (9 taps x 112 oc x 32 ic) into LDS ----
#pragma unroll
        for (int it = 0; it < 8; ++it) {
            int u = tid + it * 512;            // over (t:9, oc:112, hq:4) = 4032 units
            if (u < 4032) {
                int t = u / 448; int rem = u - t * 448;
                int oc = rem >> 2; int hq2 = rem & 3;
                *(bf16x8*)&wl[(size_t)((t * 4 + hq2) * 112 + oc) * 8] =
                    *(const bf16x8*)(WT + (size_t)((t * 4 + s) * 112 + oc) * 32 + hq2 * 8);
            }
        }
        __syncthreads();

        // ---- 9 taps ----
#pragma unroll
        for (int ky = 0; ky < 3; ++ky) {
#pragma unroll
            for (int kx = 0; kx < 3; ++kx) {
                int t = ky * 3 + kx;
                bf16x8 a[7];
#pragma unroll
                for (int f = 0; f < 7; f++)
                    a[f] = *(const bf16x8*)&wl[(size_t)((t * 4 + hq) * 112 + f * 16 + l16) * 8];
                bf16x8 bfr[4];
#pragma unroll
                for (int n = 0; n < 4; n++)
                    bfr[n] = *(const bf16x8*)&il[((wid + ky) * 72 + kx + l16 + n * 16) * 40 + hq * 8];
#pragma unroll
                for (int f = 0; f < 7; f++)
#pragma unroll
                    for (int n = 0; n < 4; n++)
                        acc[f][n] = __builtin_amdgcn_mfma_f32_16x16x32_bf16(
                            a[f], bfr[n], acc[f][n], 0, 0, 0);
            }
        }
    }

    if (yo < ow) {
#pragma unroll
        for (int f = 0; f < 7; f++) {
#pragma unroll
            for (int r = 0; r < 4; r++) {
                int oc = f * 16 + hq * 4 + r;
                if (oc < OC) {
#pragma unroll
                    for (int n = 0; n < 4; n++) {
                        int x = n * 16 + l16;
                        if (x < ow)
                            out[((size_t)(b * OC + oc) * ow + yo) * ow + x] =
                                __float2bfloat16(fmaxf(acc[f][n][r], 0.f));
                    }
                }
            }
        }
    }
}

// ---------------- generic MFMA GEMM: C[M,N] = A[M,K] @ B[N,K]^T (+bias, +relu) ----------------
// A bf16; B bf16 or f32 (converted during staging); 64x64x64 tile, 4 waves.
template<typename TB, typename TC, int ACT>
__global__ __launch_bounds__(256)
void gemm_mfma(const bf16* __restrict__ A, int lda,
               const TB* __restrict__ B, int ldb,
               const float* __restrict__ bias,
               TC* __restrict__ C, int ldc,
               int M, int N, int K)
{
    __shared__ bf16 As[64 * 72];
    __shared__ bf16 Bs[64 * 72];
    int tid = threadIdx.x;
    int l = tid & 63, wid = tid >> 6;
    int l16 = l & 15, h = l >> 4;
    int m0 = blockIdx.x * 64, n0 = blockIdx.y * 64;
    f32x4 acc[4];
#pragma unroll
    for (int nb = 0; nb < 4; nb++) acc[nb] = (f32x4){0.f, 0.f, 0.f, 0.f};

    int rs = tid >> 3;             // 0..31 staging row
    int kc = (tid & 7) * 8;        // 0..56 staging k-col

    for (int k0 = 0; k0 < K; k0 += 64) {
        int kr = K - k0;
#pragma unroll
        for (int half = 0; half < 2; half++) {
            int rr = rs + half * 32;
            bf16x8 av = {0, 0, 0, 0, 0, 0, 0, 0};
            int m = m0 + rr;
            if (m < M) {
                const short* src = (const short*)(A + (size_t)m * lda + k0 + kc);
                if (kc + 8 <= kr) av = *(const bf16x8*)src;
                else if (kc < kr) {
                    for (int j = 0; j < 8; j++) if (kc + j < kr) ((short*)&av)[j] = src[j];
                }
            }
            *(bf16x8*)&As[rr * 72 + kc] = av;
            bf16x8 bv = {0, 0, 0, 0, 0, 0, 0, 0};
            int n = n0 + rr;
            if (n < N) {
                const TB* src = B + (size_t)n * ldb + k0 + kc;
                if (kc + 8 <= kr) bv = load8(src);
                else if (kc < kr) {
                    for (int j = 0; j < 8; j++) if (kc + j < kr) ((short*)&bv)[j] = f2bs(ldf(src + j));
                }
            }
            *(bf16x8*)&Bs[rr * 72 + kc] = bv;
        }
        __syncthreads();
#pragma unroll
        for (int kk = 0; kk < 2; kk++) {
            bf16x8 af = *(const bf16x8*)&As[(wid * 16 + l16) * 72 + kk * 32 + h * 8];
#pragma unroll
            for (int nb = 0; nb < 4; nb++) {
                bf16x8 bfr = *(const bf16x8*)&Bs[(nb * 16 + l16) * 72 + kk * 32 + h * 8];
                acc[nb] = __builtin_amdgcn_mfma_f32_16x16x32_bf16(af, bfr, acc[nb], 0, 0, 0);
            }
        }
        __syncthreads();
    }
#pragma unroll
    for (int nb = 0; nb < 4; nb++) {
        int col = n0 + nb * 16 + l16;
        if (col >= N) continue;
        float bv = bias ? bias[col] : 0.f;
#pragma unroll
        for (int reg = 0; reg < 4; reg++) {
            int row = m0 + wid * 16 + h * 4 + reg;
            if (row < M) {
                float v = acc[nb][reg] + bv;
                if (ACT == 1) v = fmaxf(v, 0.f);
                stf(&C[(size_t)row * ldc + col], v);
            }
        }
    }
}

// ---------------- small fp32 GEMM (kept for tiny HB matmul) ----------------
template<typename TA, typename TC, int BM, int BN, int BK, int TM, int TN, int ACT>
__global__ __launch_bounds__((BM / TM) * (BN / TN))
void gemm_tn(const TA* __restrict__ A, int lda,
             const float* __restrict__ Bmat, int ldb,
             const float* __restrict__ bias,
             TC* __restrict__ C, int ldc,
             int M, int N, int K)
{
    constexpr int TX = BN / TN;
    constexpr int TY = BM / TM;
    constexpr int NT = TX * TY;
    __shared__ float As[BK][BM + 1];
    __shared__ float Bs[BK][BN + 1];
    int tid = threadIdx.x;
    int tx = tid % TX, ty = tid / TX;
    int m0 = blockIdx.x * BM, n0 = blockIdx.y * BN;
    float acc[TM][TN] = {};
    for (int k0 = 0; k0 < K; k0 += BK) {
        for (int idx = tid; idx < BM * BK; idx += NT) {
            int i = idx / BK, j = idx % BK;
            int m = m0 + i, k = k0 + j;
            As[j][i] = (m < M && k < K) ? ldf(&A[(size_t)m * lda + k]) : 0.f;
        }
        for (int idx = tid; idx < BN * BK; idx += NT) {
            int i = idx / BK, j = idx % BK;
            int n = n0 + i, k = k0 + j;
            Bs[j][i] = (n < N && k < K) ? Bmat[(size_t)n * ldb + k] : 0.f;
        }
        __syncthreads();
#pragma unroll
        for (int k = 0; k < BK; ++k) {
            float av[TM], bv[TN];
#pragma unroll
            for (int i = 0; i < TM; i++) av[i] = As[k][ty * TM + i];
#pragma unroll
            for (int j = 0; j < TN; j++) bv[j] = Bs[k][tx * TN + j];
#pragma unroll
            for (int i = 0; i < TM; i++)
#pragma unroll
                for (int j = 0; j < TN; j++)
                    acc[i][j] += av[i] * bv[j];
        }
        __syncthreads();
    }
#pragma unroll
    for (int i = 0; i < TM; i++) {
        int m = m0 + ty * TM + i;
        if (m >= M) continue;
#pragma unroll
        for (int j = 0; j < TN; j++) {
            int n = n0 + tx * TN + j;
            if (n >= N) continue;
            float v = acc[i][j] + (bias ? bias[n] : 0.f);
            if (ACT == 1) v = fmaxf(v, 0.f);
            stf(&C[(size_t)m * ldc + n], v);
        }
    }
}

// ---------------- LSTM recurrence: VALU gemv, bf16 weights (halved L2 stream) ----------------
// 128 blocks x 512 thr; thread g owns gate-row g. r4 structure (known-good) with
// bf16-packed Whh: 256 B/thread/step instead of 512 B (r4 was L2-BW-bound at 34.5 TB/s).
__global__ __launch_bounds__(512, 1)
void lstm_recur(const bf16* __restrict__ G,    // [B,T,512] x-part + biases
                const bf16* __restrict__ LWr,  // [512,128] bf16 row-major
                bf16* __restrict__ Y,          // [B,T,128] or nullptr
                float* __restrict__ HN,        // [B,256]
                int hoff)
{
    __shared__ __align__(16) float hl[HD];
    __shared__ float ex[G4];
    int g = threadIdx.x;
    int b = blockIdx.x;
    uint4 wv[16];                              // 128 bf16 = 64 VGPRs
    const uint4* wp = (const uint4*)(LWr + (size_t)g * HD);
#pragma unroll
    for (int q = 0; q < 16; q++) wv[q] = wp[q];
    // pin per 32-bit component ("+v" on uint4 fails: tied indirect register inputs)
#pragma unroll
    for (int q = 0; q < 16; q++)
        asm volatile("" : "+v"(wv[q].x), "+v"(wv[q].y), "+v"(wv[q].z), "+v"(wv[q].w));
    float c = 0.f;
    if (g < HD) hl[g] = 0.f;
    __syncthreads();
    const bf16* Gb = G + (size_t)b * TT * G4 + g;
    for (int t = 0; t < TT; ++t) {
        float dot = __bfloat162float(Gb[(size_t)t * G4]);
        float a0 = 0.f, a1 = 0.f, a2 = 0.f, a3 = 0.f;
#pragma unroll
        for (int q = 0; q < 16; q += 2) {
            float4 h0 = *(const float4*)&hl[q * 8];
            float4 h1 = *(const float4*)&hl[q * 8 + 4];
            float4 h2 = *(const float4*)&hl[q * 8 + 8];
            float4 h3 = *(const float4*)&hl[q * 8 + 12];
            uint4 u = wv[q];
            uint4 v = wv[q + 1];
            a0 = fmaf(ubl(u.x), h0.x, a0); a0 = fmaf(ubh(u.x), h0.y, a0);
            a1 = fmaf(ubl(u.y), h0.z, a1); a1 = fmaf(ubh(u.y), h0.w, a1);
            a2 = fmaf(ubl(u.z), h1.x, a2); a2 = fmaf(ubh(u.z), h1.y, a2);
            a3 = fmaf(ubl(u.w), h1.z, a3); a3 = fmaf(ubh(u.w), h1.w, a3);
            a0 = fmaf(ubl(v.x), h2.x, a0); a0 = fmaf(ubh(v.x), h2.y, a0);
            a1 = fmaf(ubl(v.y), h2.z, a1); a1 = fmaf(ubh(v.y), h2.w, a1);
            a2 = fmaf(ubl(v.z), h3.x, a2); a2 = fmaf(ubh(v.z), h3.y, a2);
            a3 = fmaf(ubl(v.w), h3.z, a3); a3 = fmaf(ubh(v.w), h3.w, a3);
        }
        dot += (a0 + a1) + (a2 + a3);
        float tr;
        if (g < 2 * HD || g >= 3 * HD) tr = fsig(dot);   // i,f,o
        else tr = ftanh(dot);                             // g
        ex[g] = tr;
        __syncthreads();
        if (g < HD) {
            float iv = ex[g], fv = ex[HD + g], gv = ex[2 * HD + g], ov = ex[3 * HD + g];
            c = fv * c + iv * gv;
            float nh = ov * ftanh(c);
            hl[g] = nh;
            if (Y) Y[((size_t)b * TT + t) * HD + g] = __float2bfloat16(nh);
            if (t == TT - 1) HN[(size_t)b * 256 + hoff + g] = nh;
        }
        __syncthreads();
    }
}

// ---------------- small helpers ----------------
__global__ void bias_sum(const float* a, const float* b, float* o, int n)
{
    int i = blockIdx.x * 256 + threadIdx.x;
    if (i < n) o[i] = a[i] + b[i];
}

// fused attention logits + softmax: one block per batch row
__global__ __launch_bounds__(128)
void attn_softmax(const float* __restrict__ T1,  // [BC*OC,64] (chunk base)
                  const float* __restrict__ HB,  // [BC,64] (chunk base, includes attn1_b)
                  const float* __restrict__ a2w, // [64]
                  const float* __restrict__ a2b, // [1]
                  float* __restrict__ ATT)       // [BC,100]
{
    __shared__ float hbl[ANF];
    __shared__ float awl[ANF];
    __shared__ float red[128];
    int b = blockIdx.x, tid = threadIdx.x;
    if (tid < ANF) { hbl[tid] = HB[b * ANF + tid]; awl[tid] = a2w[tid]; }
    __syncthreads();
    float lg = -1e30f;
    if (tid < OC) {
        const float* tp = T1 + (size_t)(b * OC + tid) * ANF;
        float s = 0.f;
#pragma unroll 4
        for (int j = 0; j < ANF; j++) s += ftanh(tp[j] + hbl[j]) * awl[j];
        lg = s + a2b[0];
    }
    red[tid] = lg; __syncthreads();
    for (int st = 64; st > 0; st >>= 1) { if (tid < st) red[tid] = fmaxf(red[tid], red[tid + st]); __syncthreads(); }
    float mx = red[0]; __syncthreads();
    float e = (tid < OC) ? __expf(lg - mx) : 0.f;
    red[tid] = e; __syncthreads();
    for (int st = 64; st > 0; st >>= 1) { if (tid < st) red[tid] += red[tid + st]; __syncthreads(); }
    if (tid < OC) ATT[b * OC + tid] = e / red[0];
}

__global__ __launch_bounds__(256)
void ctx_concat(const bf16* __restrict__ XD,   // [BC,100,3364]
                const float* __restrict__ ATT, // [BC,100]
                const float* __restrict__ HN,  // [BC,256] (chunk base)
                bf16* __restrict__ M)          // [BC,3620] bf16 (chunk base)
{
    __shared__ float al[OC];
    int b = blockIdx.x;
    int tid = threadIdx.x;
    if (tid < OC) al[tid] = ATT[b * OC + tid];
    __syncthreads();
    int s = blockIdx.y * 256 + tid;
    if (s < SS) {
        const bf16* xp = XD + (size_t)b * OC * SS + s;
        float acc = 0.f;
#pragma unroll 4
        for (int c = 0; c < OC; c++) acc = fmaf(__bfloat162float(xp[(size_t)c * SS]), al[c], acc);
        M[(size_t)b * FF + s] = __float2bfloat16(acc);
    } else if (s < FF) {
        M[(size_t)b * FF + s] = __float2bfloat16(HN[b * 256 + (s - SS)]);
    }
}

__global__ __launch_bounds__(256)
void fc2_kernel(const float* __restrict__ H1, // [128,1810]
                const float* __restrict__ w,  // [1810]
                const float* __restrict__ bias,
                float* __restrict__ out)      // [128]
{
    int tid = threadIdx.x;
    int lane = tid & 63, wid = tid >> 6;
    int b = blockIdx.x * 4 + wid;
    float acc = 0.f;
    for (int j = lane; j < HIDN; j += 64) acc = fmaf(H1[(size_t)b * HIDN + j], w[j], acc);
#pragma unroll
    for (int off = 32; off > 0; off >>= 1) acc += __shfl_down(acc, off, 64);
    if (lane == 0) out[b] = acc + bias[0];
}

extern "C" void kernel_launch(void* const* d_in, const int* in_sizes, int n_in,
                              void* d_out, int out_size, void* d_ws, size_t ws_size,
                              hipStream_t stream)
{
    const float* x1   = (const float*)d_in[0];
    const float* x2   = (const float*)d_in[1];
    const float* c1w  = (const float*)d_in[2];
    const float* c1b  = (const float*)d_in[3];
    const float* c2aw = (const float*)d_in[4];
    const float* c2ab = (const float*)d_in[5];
    const float* c2bw = (const float*)d_in[6];
    const float* c2bb = (const float*)d_in[7];
    const float* wih0 = (const float*)d_in[8];
    const float* whh0 = (const float*)d_in[9];
    const float* bih0 = (const float*)d_in[10];
    const float* bhh0 = (const float*)d_in[11];
    const float* wih1 = (const float*)d_in[12];
    const float* whh1 = (const float*)d_in[13];
    const float* bih1 = (const float*)d_in[14];
    const float* bhh1 = (const float*)d_in[15];
    const float* a1w  = (const float*)d_in[16];
    const float* a1b  = (const float*)d_in[17];
    const float* a2w  = (const float*)d_in[18];
    const float* a2b  = (const float*)d_in[19];
    const float* f1w  = (const float*)d_in[20];
    const float* f1b  = (const float*)d_in[21];
    const float* f2w  = (const float*)d_in[22];
    const float* f2b  = (const float*)d_in[23];
    float* out = (float*)d_out;

    // ---- workspace layout (arena with phase overlays; offsets 256B aligned) ----
    char* base = (char*)d_ws;
    bf16* G0    = (bf16*)(base + 0);            // 33,554,432
    bf16* Y0    = (bf16*)(base + 33554432);     //  8,388,608
    bf16* G1    = G0;                           // reuse
    bf16* X2B   = (bf16*)(base + 41943040);     //  4,194,304
    bf16* WIH0B = (bf16*)(base + 46137344);     //     65,536
    bf16* WIH1B = (bf16*)(base + 46202880);     //    131,072
    bf16* LW0   = (bf16*)(base + 46333952);     //    131,072 (bf16 Whh0, LSTM phase only)
    bf16* LW1   = (bf16*)(base + 46465024);     //    131,072 (end 46,596,096 < 47,641,600)
    bf16* A1c = (bf16*)(base + 0);              // 24,601,600 (CNN phase)
    bf16* A2c = (bf16*)(base + 24601600);       // 23,040,000
    bf16* XDc = A1c;
    size_t p = 47641600;
    float* BS0  = (float*)(base + p); p += 2048;
    float* BS1  = (float*)(base + p); p += 2048;
    float* HN   = (float*)(base + p); p += 131072;   // 128*256*4
    float* HB   = (float*)(base + p); p += 32768;    // 128*64*4
    float* T1c  = (float*)(base + p); p += 819200;   // 32*100*64*4
    float* ATTc = (float*)(base + p); p += 12800;
    bf16*  MBb  = (bf16*)(base + p); p += 926720;    // 128*3620*2
    float* H1   = (float*)(base + p); p += 926720;   // 128*1810*4
    bf16* WTa   = (bf16*)(base + p); p += 258048;
    bf16* WTb   = (bf16*)(base + p); p += 258048;
    bf16* A1WB  = (bf16*)(base + p); p += 463360;    // 64*3620*2
    if (ws_size < p) {
        zero_kernel<<<1, 128, 0, stream>>>(out, out_size);
        return;
    }

    // ---- weight conversions / repacks ----
    wt_repack<<<504, 256, 0, stream>>>(c2aw, WTa);
    wt_repack<<<504, 256, 0, stream>>>(c2bw, WTb);
    cvt4_bf16<<<64,   256, 0, stream>>>(whh0, LW0, 16384);     // 512*128/4
    cvt4_bf16<<<64,   256, 0, stream>>>(whh1, LW1, 16384);
    cvt4_bf16<<<2048, 256, 0, stream>>>(x2,   X2B,   524288);
    cvt4_bf16<<<32,   256, 0, stream>>>(wih0, WIH0B, 8192);
    cvt4_bf16<<<64,   256, 0, stream>>>(wih1, WIH1B, 16384);
    cvt4_bf16<<<227,  256, 0, stream>>>(a1w,  A1WB,  57920);
    bias_sum<<<2, 256, 0, stream>>>(bih0, bhh0, BS0, G4);
    bias_sum<<<2, 256, 0, stream>>>(bih1, bhh1, BS1, G4);

    // ---- LSTM branch (full batch) ----
    gemm_mfma<bf16, bf16, 0><<<dim3(512, 8), 256, 0, stream>>>(
        X2B, IDIM, WIH0B, IDIM, BS0, G0, G4, BB * TT, G4, IDIM);
    lstm_recur<<<BB, 512, 0, stream>>>(G0, LW0, Y0, HN, 0);
    gemm_mfma<bf16, bf16, 0><<<dim3(512, 8), 256, 0, stream>>>(
        Y0, HD, WIH1B, HD, BS1, G1, G4, BB * TT, G4, HD);
    lstm_recur<<<BB, 512, 0, stream>>>(G1, LW1, (bf16*)nullptr, HN, HD);

    // hn-part of attention layer 1 (full batch, once; tiny fp32)
    gemm_tn<float, float, 32, 32, 16, 2, 2, 0><<<dim3(4, 2), 256, 0, stream>>>(
        HN, 256, a1w + SS, FF, a1b, HB, ANF, BB, ANF, 256);

    // ---- CNN branch + attention + ctx, chunked over batch ----
    for (int c0 = 0; c0 < BB; c0 += BC) {
        conv1_kernel<<<dim3(BC, 16), 256, 0, stream>>>(
            x1 + (size_t)c0 * 3 * 64 * 64, c1w, c1b, A1c);
        conv2_mfma<<<dim3(BC, 8), 512, 0, stream>>>(A1c, WTa, c2ab, A2c, W1, W2);
        conv2_mfma<<<dim3(BC, 8), 512, 0, stream>>>(A2c, WTb, c2bb, XDc, W2, W3);
        gemm_mfma<bf16, float, 0><<<dim3(50, 1), 256, 0, stream>>>(
            XDc, SS, A1WB, FF, nullptr, T1c, ANF, BC * OC, ANF, SS);
        attn_softmax<<<BC, 128, 0, stream>>>(T1c, HB + (size_t)c0 * ANF, a2w, a2b, ATTc);
        ctx_concat<<<dim3(BC, 15), 256, 0, stream>>>(
            XDc, ATTc, HN + (size_t)c0 * 256, MBb + (size_t)c0 * FF);
    }

    // ---- fusion MLP (fc1 converts f32 B during staging; no pre-cvt pass) ----
    gemm_mfma<float, float, 1><<<dim3(2, 29), 256, 0, stream>>>(
        MBb, FF, f1w, FF, f1b, H1, HIDN, BB, HIDN, FF);
    fc2_kernel<<<BB / 4, 256, 0, stream>>>(H1, f2w, f2b, out);
}

// Round 10
// 1229.033 us; speedup vs baseline: 1.8876x; 1.3071x over previous
//
#include <hip/hip_runtime.h>
#include <hip/hip_bf16.h>
#include <math.h>

#define BB 128
#define TT 256
#define IDIM 64
#define HD 128
#define G4 512
#define OC 100
#define W1 62
#define W2 60
#define W3 58
#define NPX1 (W1*W1)
#define NPX2 (W2*W2)
#define NPX3 (W3*W3)
#define SS NPX3
#define FF (SS + 2*HD)
#define HIDN 1810
#define ANF 64

typedef __hip_bfloat16 bf16;
typedef _Float16 f16;
typedef __attribute__((ext_vector_type(8))) short bf16x8;
typedef __attribute__((ext_vector_type(4))) short bf16x4;
typedef __attribute__((ext_vector_type(2))) _Float16 half2v;
typedef __attribute__((ext_vector_type(4))) float f32x4;

__device__ __forceinline__ float ldf(const float* p) { return *p; }
__device__ __forceinline__ float ldf(const bf16* p)  { return __bfloat162float(*p); }
__device__ __forceinline__ void  stf(float* p, float v) { *p = v; }
__device__ __forceinline__ void  stf(bf16* p, float v)  { *p = __float2bfloat16(v); }

__device__ __forceinline__ short f2bs(float v) {
    bf16 t = __float2bfloat16(v); short s; __builtin_memcpy(&s, &t, 2); return s;
}
__device__ __forceinline__ float fsig(float x) {
    return __builtin_amdgcn_rcpf(1.f + __expf(-x));
}
__device__ __forceinline__ float ftanh(float x) {
    float t = __expf(-2.f * fabsf(x));
    float r = __builtin_amdgcn_rcpf(1.f + t);
    float m = 1.f - 2.f * t * r;
    return copysignf(m, x);
}
// packed f16 dual-FMA: clang folds (float)f16 * (float)f16 + f32 into v_fma_mix_f32
__device__ __forceinline__ float fmix2(unsigned w, unsigned h, float acc) {
    half2v wv, hv;
    __builtin_memcpy(&wv, &w, 4);
    __builtin_memcpy(&hv, &h, 4);
    acc = fmaf((float)wv[0], (float)hv[0], acc);
    acc = fmaf((float)wv[1], (float)hv[1], acc);
    return acc;
}

__device__ __forceinline__ bf16x8 load8(const bf16* p) { return *(const bf16x8*)p; }
__device__ __forceinline__ bf16x8 load8(const float* p) {
    float4 x = *(const float4*)p;
    float4 y = *(const float4*)(p + 4);
    bf16x8 r;
    r[0] = f2bs(x.x); r[1] = f2bs(x.y); r[2] = f2bs(x.z); r[3] = f2bs(x.w);
    r[4] = f2bs(y.x); r[5] = f2bs(y.y); r[6] = f2bs(y.z); r[7] = f2bs(y.w);
    return r;
}

__global__ void zero_kernel(float* o, int n)
{
    int i = blockIdx.x * 256 + threadIdx.x;
    if (i < n) o[i] = 0.f;
}

// ---------------- fp32 -> bf16 / f16 vectorized converts ----------------
__global__ __launch_bounds__(256)
void cvt4_bf16(const float* __restrict__ s, bf16* __restrict__ d, int n4)
{
    int i = blockIdx.x * 256 + threadIdx.x;
    if (i >= n4) return;
    float4 v = ((const float4*)s)[i];
    bf16x4 o;
    o[0] = f2bs(v.x); o[1] = f2bs(v.y); o[2] = f2bs(v.z); o[3] = f2bs(v.w);
    *(bf16x4*)(d + 4 * (size_t)i) = o;
}

__global__ __launch_bounds__(256)
void cvt4_f16(const float* __restrict__ s, f16* __restrict__ d, int n4)
{
    int i = blockIdx.x * 256 + threadIdx.x;
    if (i >= n4) return;
    float4 v = ((const float4*)s)[i];
    f16 o[4] = {(f16)v.x, (f16)v.y, (f16)v.z, (f16)v.w};
    *(uint2*)(d + 4 * (size_t)i) = *(uint2*)o;
}

// ---------------- conv1: [nb,3,64,64] -> relu -> [nb,100,62,62] (bf16 out) ----------------
__global__ __launch_bounds__(256)
void conv1_kernel(const float* __restrict__ x1,
                  const float* __restrict__ w,     // [100,3,3,3]
                  const float* __restrict__ bias,  // [100]
                  bf16* __restrict__ out)          // [nb,100,62,62]
{
    __shared__ float wl[2700];
    __shared__ float bl[OC];
    int tid = threadIdx.x;
    for (int i = tid; i < 2700; i += 256) wl[i] = w[i];
    if (tid < OC) bl[tid] = bias[tid];
    __syncthreads();
    int b  = blockIdx.x;
    int px = blockIdx.y * 256 + tid;
    if (px >= NPX1) return;
    int y = px / W1, x = px % W1;
    float in[3][3][3];
    const float* xb = x1 + (size_t)b * 3 * 64 * 64;
#pragma unroll
    for (int ic = 0; ic < 3; ic++)
#pragma unroll
        for (int r = 0; r < 3; r++)
#pragma unroll
            for (int c = 0; c < 3; c++)
                in[ic][r][c] = xb[(ic * 64 + y + r) * 64 + x + c];
    bf16* ob = out + (size_t)b * OC * NPX1 + px;
    for (int oc = 0; oc < OC; ++oc) {
        float acc = bl[oc];
        const float* wp = &wl[oc * 27];
#pragma unroll
        for (int ic = 0; ic < 3; ic++)
#pragma unroll
            for (int r = 0; r < 3; r++)
#pragma unroll
                for (int c = 0; c < 3; c++)
                    acc = fmaf(in[ic][r][c], wp[ic * 9 + r * 3 + c], acc);
        ob[(size_t)oc * NPX1] = __float2bfloat16(fmaxf(acc, 0.f));
    }
}

// ---------------- conv2 weight repack: fp32 [oc][ic][3][3] -> bf16 WT[t][s][oc112][i32] ----------------
__global__ __launch_bounds__(256)
void wt_repack(const float* __restrict__ w, bf16* __restrict__ WT)
{
    int idx = blockIdx.x * 256 + threadIdx.x;   // over 9*4*112*32 = 129024
    if (idx >= 129024) return;
    int i  = idx & 31;
    int oc = (idx >> 5) % 112;
    int ts = idx / (112 * 32);   // t*4+s
    int s = ts & 3, t = ts >> 2;
    int ic = s * 32 + i;
    float v = 0.f;
    if (oc < OC && ic < OC) v = w[(oc * OC + ic) * 9 + t];
    WT[idx] = __float2bfloat16(v);
}

// ---------------- conv2 via MFMA implicit GEMM ----------------
__global__ __launch_bounds__(512, 1)
void conv2_mfma(const bf16* __restrict__ in,   // [nb,100,iw,iw]
                const bf16* __restrict__ WT,   // [9][4][112][32] bf16
                const float* __restrict__ bias,
                bf16* __restrict__ out,        // [nb,100,ow,ow]
                int iw, int ow)
{
    __shared__ bf16 il[10 * 72 * 40];
    __shared__ bf16 wl[4032 * 8];
    int tid = threadIdx.x;
    int b = blockIdx.x;
    int y0 = blockIdx.y * 8;
    int wid = tid >> 6;
    int l = tid & 63;
    int hq = l >> 4;
    int l16 = l & 15;
    int yo = y0 + wid;

    f32x4 acc[7][4];
#pragma unroll
    for (int f = 0; f < 7; f++) {
#pragma unroll
        for (int r = 0; r < 4; r++) {
            int oc = f * 16 + hq * 4 + r;
            float bv = (oc < OC) ? bias[oc] : 0.f;
#pragma unroll
            for (int n = 0; n < 4; n++) acc[f][n][r] = bv;
        }
    }

    const size_t ims = (size_t)iw * iw;
    int icl = tid & 31;
    int t2  = tid >> 5;
    for (int s = 0; s < 4; ++s) {
        __syncthreads();
        int ic = s * 32 + icl;
        bool icok = ic < OC;
        const bf16* ibase = in + (size_t)(b * OC + ic) * ims;
#pragma unroll
        for (int it = 0; it < 6; ++it) {
            int u2 = t2 + it * 16;
            if (u2 < 90) {
                int r = u2 / 9, xb = u2 - r * 9;
                int x8 = xb * 8;
                int yy = y0 + r;
                bf16x8 v = {0, 0, 0, 0, 0, 0, 0, 0};
                if (icok && yy < iw && x8 < iw) {
                    const short* sp = (const short*)(ibase + (size_t)yy * iw + x8);
                    if (x8 + 8 <= iw) {
                        const unsigned* sp32 = (const unsigned*)sp;
#pragma unroll
                        for (int q = 0; q < 4; q++)
                            ((unsigned*)&v)[q] = sp32[q];
                    } else {
                        for (int k = 0; k < 8; k++)
                            if (x8 + k < iw) ((short*)&v)[k] = sp[k];
                    }
                }
                bf16* dst = &il[(r * 72 + x8) * 40 + icl];
#pragma unroll
                for (int k = 0; k < 8; k++)
                    *(short*)&dst[k * 40] = ((short*)&v)[k];
            }
        }
#pragma unroll
        for (int it = 0; it < 8; ++it) {
            int u = tid + it * 512;
            if (u < 4032) {
                int t = u / 448; int rem = u - t * 448;
                int oc = rem >> 2; int hq2 = rem & 3;
                *(bf16x8*)&wl[(size_t)((t * 4 + hq2) * 112 + oc) * 8] =
                    *(const bf16x8*)(WT + (size_t)((t * 4 + s) * 112 + oc) * 32 + hq2 * 8);
            }
        }
        __syncthreads();

#pragma unroll
        for (int ky = 0; ky < 3; ++ky) {
#pragma unroll
            for (int kx = 0; kx < 3; ++kx) {
                int t = ky * 3 + kx;
                bf16x8 a[7];
#pragma unroll
                for (int f = 0; f < 7; f++)
                    a[f] = *(const bf16x8*)&wl[(size_t)((t * 4 + hq) * 112 + f * 16 + l16) * 8];
                bf16x8 bfr[4];
#pragma unroll
                for (int n = 0; n < 4; n++)
                    bfr[n] = *(const bf16x8*)&il[((wid + ky) * 72 + kx + l16 + n * 16) * 40 + hq * 8];
#pragma unroll
                for (int f = 0; f < 7; f++)
#pragma unroll
                    for (int n = 0; n < 4; n++)
                        acc[f][n] = __builtin_amdgcn_mfma_f32_16x16x32_bf16(
                            a[f], bfr[n], acc[f][n], 0, 0, 0);
            }
        }
    }

    if (yo < ow) {
#pragma unroll
        for (int f = 0; f < 7; f++) {
#pragma unroll
            for (int r = 0; r < 4; r++) {
                int oc = f * 16 + hq * 4 + r;
                if (oc < OC) {
#pragma unroll
                    for (int n = 0; n < 4; n++) {
                        int x = n * 16 + l16;
                        if (x < ow)
                            out[((size_t)(b * OC + oc) * ow + yo) * ow + x] =
                                __float2bfloat16(fmaxf(acc[f][n][r], 0.f));
                    }
                }
            }
        }
    }
}

// ---------------- generic MFMA GEMM: C[M,N] = A[M,K] @ B[N,K]^T (+bias, +relu) ----------------
template<typename TB, typename TC, int ACT>
__global__ __launch_bounds__(256)
void gemm_mfma(const bf16* __restrict__ A, int lda,
               const TB* __restrict__ B, int ldb,
               const float* __restrict__ bias,
               TC* __restrict__ C, int ldc,
               int M, int N, int K)
{
    __shared__ bf16 As[64 * 72];
    __shared__ bf16 Bs[64 * 72];
    int tid = threadIdx.x;
    int l = tid & 63, wid = tid >> 6;
    int l16 = l & 15, h = l >> 4;
    int m0 = blockIdx.x * 64, n0 = blockIdx.y * 64;
    f32x4 acc[4];
#pragma unroll
    for (int nb = 0; nb < 4; nb++) acc[nb] = (f32x4){0.f, 0.f, 0.f, 0.f};

    int rs = tid >> 3;
    int kc = (tid & 7) * 8;

    for (int k0 = 0; k0 < K; k0 += 64) {
        int kr = K - k0;
#pragma unroll
        for (int half = 0; half < 2; half++) {
            int rr = rs + half * 32;
            bf16x8 av = {0, 0, 0, 0, 0, 0, 0, 0};
            int m = m0 + rr;
            if (m < M) {
                const short* src = (const short*)(A + (size_t)m * lda + k0 + kc);
                if (kc + 8 <= kr) av = *(const bf16x8*)src;
                else if (kc < kr) {
                    for (int j = 0; j < 8; j++) if (kc + j < kr) ((short*)&av)[j] = src[j];
                }
            }
            *(bf16x8*)&As[rr * 72 + kc] = av;
            bf16x8 bv = {0, 0, 0, 0, 0, 0, 0, 0};
            int n = n0 + rr;
            if (n < N) {
                const TB* src = B + (size_t)n * ldb + k0 + kc;
                if (kc + 8 <= kr) bv = load8(src);
                else if (kc < kr) {
                    for (int j = 0; j < 8; j++) if (kc + j < kr) ((short*)&bv)[j] = f2bs(ldf(src + j));
                }
            }
            *(bf16x8*)&Bs[rr * 72 + kc] = bv;
        }
        __syncthreads();
#pragma unroll
        for (int kk = 0; kk < 2; kk++) {
            bf16x8 af = *(const bf16x8*)&As[(wid * 16 + l16) * 72 + kk * 32 + h * 8];
#pragma unroll
            for (int nb = 0; nb < 4; nb++) {
                bf16x8 bfr = *(const bf16x8*)&Bs[(nb * 16 + l16) * 72 + kk * 32 + h * 8];
                acc[nb] = __builtin_amdgcn_mfma_f32_16x16x32_bf16(af, bfr, acc[nb], 0, 0, 0);
            }
        }
        __syncthreads();
    }
#pragma unroll
    for (int nb = 0; nb < 4; nb++) {
        int col = n0 + nb * 16 + l16;
        if (col >= N) continue;
        float bv = bias ? bias[col] : 0.f;
#pragma unroll
        for (int reg = 0; reg < 4; reg++) {
            int row = m0 + wid * 16 + h * 4 + reg;
            if (row < M) {
                float v = acc[nb][reg] + bv;
                if (ACT == 1) v = fmaxf(v, 0.f);
                stf(&C[(size_t)row * ldc + col], v);
            }
        }
    }
}

// ---------------- small fp32 GEMM (kept for tiny HB matmul) ----------------
template<typename TA, typename TC, int BM, int BN, int BK, int TM, int TN, int ACT>
__global__ __launch_bounds__((BM / TM) * (BN / TN))
void gemm_tn(const TA* __restrict__ A, int lda,
             const float* __restrict__ Bmat, int ldb,
             const float* __restrict__ bias,
             TC* __restrict__ C, int ldc,
             int M, int N, int K)
{
    constexpr int TX = BN / TN;
    constexpr int TY = BM / TM;
    constexpr int NT = TX * TY;
    __shared__ float As[BK][BM + 1];
    __shared__ float Bs[BK][BN + 1];
    int tid = threadIdx.x;
    int tx = tid % TX, ty = tid / TX;
    int m0 = blockIdx.x * BM, n0 = blockIdx.y * BN;
    float acc[TM][TN] = {};
    for (int k0 = 0; k0 < K; k0 += BK) {
        for (int idx = tid; idx < BM * BK; idx += NT) {
            int i = idx / BK, j = idx % BK;
            int m = m0 + i, k = k0 + j;
            As[j][i] = (m < M && k < K) ? ldf(&A[(size_t)m * lda + k]) : 0.f;
        }
        for (int idx = tid; idx < BN * BK; idx += NT) {
            int i = idx / BK, j = idx % BK;
            int n = n0 + i, k = k0 + j;
            Bs[j][i] = (n < N && k < K) ? Bmat[(size_t)n * ldb + k] : 0.f;
        }
        __syncthreads();
#pragma unroll
        for (int k = 0; k < BK; ++k) {
            float av[TM], bv[TN];
#pragma unroll
            for (int i = 0; i < TM; i++) av[i] = As[k][ty * TM + i];
#pragma unroll
            for (int j = 0; j < TN; j++) bv[j] = Bs[k][tx * TN + j];
#pragma unroll
            for (int i = 0; i < TM; i++)
#pragma unroll
                for (int j = 0; j < TN; j++)
                    acc[i][j] += av[i] * bv[j];
        }
        __syncthreads();
    }
#pragma unroll
    for (int i = 0; i < TM; i++) {
        int m = m0 + ty * TM + i;
        if (m >= M) continue;
#pragma unroll
        for (int j = 0; j < TN; j++) {
            int n = n0 + tx * TN + j;
            if (n >= N) continue;
            float v = acc[i][j] + (bias ? bias[n] : 0.f);
            if (ACT == 1) v = fmaxf(v, 0.f);
            stf(&C[(size_t)m * ldc + n], v);
        }
    }
}

// ---------------- LSTM recurrence: VALU gemv, f16 weights + v_fma_mix ----------------
// 128 blocks x 512 thr; thread g owns gate-row g. f16 weights+h: the
// (float)f16*(float)f16+f32 pattern folds to v_fma_mix_f32 (no unpack ops) --
// per-step VALU ops drop ~2x vs r9's bf16 shift/and unpacking.
__global__ __launch_bounds__(512, 1)
void lstm_recur(const bf16* __restrict__ G,    // [B,T,512] x-part + biases
                const f16* __restrict__ LWr,   // [512,128] f16 row-major
                bf16* __restrict__ Y,          // [B,T,128] or nullptr
                float* __restrict__ HN,        // [B,256]
                int hoff)
{
    __shared__ __align__(16) f16 hl[HD];
    __shared__ float ex[G4];
    int g = threadIdx.x;
    int b = blockIdx.x;
    uint4 wv[16];                              // 128 f16 = 64 VGPRs
    const uint4* wp = (const uint4*)(LWr + (size_t)g * HD);
#pragma unroll
    for (int q = 0; q < 16; q++) wv[q] = wp[q];
#pragma unroll
    for (int q = 0; q < 16; q++)
        asm volatile("" : "+v"(wv[q].x), "+v"(wv[q].y), "+v"(wv[q].z), "+v"(wv[q].w));
    float c = 0.f;
    if (g < HD) hl[g] = (f16)0.f;
    __syncthreads();
    const bf16* Gb = G + (size_t)b * TT * G4 + g;
    for (int t = 0; t < TT; ++t) {
        float dot = __bfloat162float(Gb[(size_t)t * G4]);
        float a0 = 0.f, a1 = 0.f, a2 = 0.f, a3 = 0.f;
#pragma unroll
        for (int q = 0; q < 16; q++) {
            uint4 hw = *(const uint4*)&hl[q * 8];
            a0 = fmix2(wv[q].x, hw.x, a0);
            a1 = fmix2(wv[q].y, hw.y, a1);
            a2 = fmix2(wv[q].z, hw.z, a2);
            a3 = fmix2(wv[q].w, hw.w, a3);
        }
        dot += (a0 + a1) + (a2 + a3);
        float tr;
        if (g < 2 * HD || g >= 3 * HD) tr = fsig(dot);   // i,f,o
        else tr = ftanh(dot);                             // g
        ex[g] = tr;
        __syncthreads();
        if (g < HD) {
            float iv = ex[g], fv = ex[HD + g], gv = ex[2 * HD + g], ov = ex[3 * HD + g];
            c = fv * c + iv * gv;
            float nh = ov * ftanh(c);
            hl[g] = (f16)nh;
            if (Y) Y[((size_t)b * TT + t) * HD + g] = __float2bfloat16(nh);
            if (t == TT - 1) HN[(size_t)b * 256 + hoff + g] = nh;
        }
        __syncthreads();
    }
}

// ---------------- small helpers ----------------
__global__ void bias_sum(const float* a, const float* b, float* o, int n)
{
    int i = blockIdx.x * 256 + threadIdx.x;
    if (i < n) o[i] = a[i] + b[i];
}

__global__ __launch_bounds__(128)
void attn_softmax(const float* __restrict__ T1,  // [nb*OC,64]
                  const float* __restrict__ HB,  // [nb,64] (chunk base, includes attn1_b)
                  const float* __restrict__ a2w, // [64]
                  const float* __restrict__ a2b, // [1]
                  float* __restrict__ ATT)       // [nb,100]
{
    __shared__ float hbl[ANF];
    __shared__ float awl[ANF];
    __shared__ float red[128];
    int b = blockIdx.x, tid = threadIdx.x;
    if (tid < ANF) { hbl[tid] = HB[b * ANF + tid]; awl[tid] = a2w[tid]; }
    __syncthreads();
    float lg = -1e30f;
    if (tid < OC) {
        const float* tp = T1 + (size_t)(b * OC + tid) * ANF;
        float s = 0.f;
#pragma unroll 4
        for (int j = 0; j < ANF; j++) s += ftanh(tp[j] + hbl[j]) * awl[j];
        lg = s + a2b[0];
    }
    red[tid] = lg; __syncthreads();
    for (int st = 64; st > 0; st >>= 1) { if (tid < st) red[tid] = fmaxf(red[tid], red[tid + st]); __syncthreads(); }
    float mx = red[0]; __syncthreads();
    float e = (tid < OC) ? __expf(lg - mx) : 0.f;
    red[tid] = e; __syncthreads();
    for (int st = 64; st > 0; st >>= 1) { if (tid < st) red[tid] += red[tid + st]; __syncthreads(); }
    if (tid < OC) ATT[b * OC + tid] = e / red[0];
}

__global__ __launch_bounds__(256)
void ctx_concat(const bf16* __restrict__ XD,   // [nb,100,3364]
                const float* __restrict__ ATT, // [nb,100]
                const float* __restrict__ HN,  // [nb,256] (chunk base)
                bf16* __restrict__ M)          // [nb,3620] bf16 (chunk base)
{
    __shared__ float al[OC];
    int b = blockIdx.x;
    int tid = threadIdx.x;
    if (tid < OC) al[tid] = ATT[b * OC + tid];
    __syncthreads();
    int s = blockIdx.y * 256 + tid;
    if (s < SS) {
        const bf16* xp = XD + (size_t)b * OC * SS + s;
        float acc = 0.f;
#pragma unroll 4
        for (int c = 0; c < OC; c++) acc = fmaf(__bfloat162float(xp[(size_t)c * SS]), al[c], acc);
        M[(size_t)b * FF + s] = __float2bfloat16(acc);
    } else if (s < FF) {
        M[(size_t)b * FF + s] = __float2bfloat16(HN[b * 256 + (s - SS)]);
    }
}

__global__ __launch_bounds__(256)
void fc2_kernel(const float* __restrict__ H1, // [128,1810]
                const float* __restrict__ w,  // [1810]
                const float* __restrict__ bias,
                float* __restrict__ out)      // [128]
{
    int tid = threadIdx.x;
    int lane = tid & 63, wid = tid >> 6;
    int b = blockIdx.x * 4 + wid;
    float acc = 0.f;
    for (int j = lane; j < HIDN; j += 64) acc = fmaf(H1[(size_t)b * HIDN + j], w[j], acc);
#pragma unroll
    for (int off = 32; off > 0; off >>= 1) acc += __shfl_down(acc, off, 64);
    if (lane == 0) out[b] = acc + bias[0];
}

extern "C" void kernel_launch(void* const* d_in, const int* in_sizes, int n_in,
                              void* d_out, int out_size, void* d_ws, size_t ws_size,
                              hipStream_t stream)
{
    const float* x1   = (const float*)d_in[0];
    const float* x2   = (const float*)d_in[1];
    const float* c1w  = (const float*)d_in[2];
    const float* c1b  = (const float*)d_in[3];
    const float* c2aw = (const float*)d_in[4];
    const float* c2ab = (const float*)d_in[5];
    const float* c2bw = (const float*)d_in[6];
    const float* c2bb = (const float*)d_in[7];
    const float* wih0 = (const float*)d_in[8];
    const float* whh0 = (const float*)d_in[9];
    const float* bih0 = (const float*)d_in[10];
    const float* bhh0 = (const float*)d_in[11];
    const float* wih1 = (const float*)d_in[12];
    const float* whh1 = (const float*)d_in[13];
    const float* bih1 = (const float*)d_in[14];
    const float* bhh1 = (const float*)d_in[15];
    const float* a1w  = (const float*)d_in[16];
    const float* a1b  = (const float*)d_in[17];
    const float* a2w  = (const float*)d_in[18];
    const float* a2b  = (const float*)d_in[19];
    const float* f1w  = (const float*)d_in[20];
    const float* f1b  = (const float*)d_in[21];
    const float* f2w  = (const float*)d_in[22];
    const float* f2b  = (const float*)d_in[23];
    float* out = (float*)d_out;

    // ---- LSTM-phase overlay (fixed offsets; dead once CNN phase starts) ----
    char* base = (char*)d_ws;
    bf16* G0    = (bf16*)(base + 0);            // 33,554,432
    bf16* Y0    = (bf16*)(base + 33554432);     //  8,388,608
    bf16* G1    = G0;                           // reuse
    bf16* X2B   = (bf16*)(base + 41943040);     //  4,194,304
    bf16* WIH0B = (bf16*)(base + 46137344);     //     65,536
    bf16* WIH1B = (bf16*)(base + 46202880);     //    131,072
    f16*  LWf0  = (f16*)(base + 46333952);      //    131,072 (f16 Whh0)
    f16*  LWf1  = (f16*)(base + 46465024);      //    131,072 (end 46,596,096)
    const size_t LSTM_END = 46596096;

    // ---- pick CNN batch-chunk size from available workspace ----
    int nb = 0; size_t ov = 0;
    for (int cand = BB; cand >= 32; cand >>= 1) {
        size_t cnn = (size_t)cand * OC * (NPX1 + NPX2) * 2;
        size_t o = cnn > LSTM_END ? cnn : LSTM_END;
        size_t q = o + 2048 + 2048 + 131072 + 32768
                 + (size_t)cand * OC * 64 * 4                      // T1c
                 + (((size_t)cand * OC * 4 + 255) & ~(size_t)255)  // ATTc
                 + 926720 + 926720 + 258048 + 258048 + 463360;
        if (ws_size >= q) { nb = cand; ov = o; break; }
    }
    if (nb == 0) {
        zero_kernel<<<1, 128, 0, stream>>>(out, out_size);
        return;
    }
    bf16* A1c = (bf16*)(base + 0);
    bf16* A2c = (bf16*)(base + (size_t)nb * OC * NPX1 * 2);
    bf16* XDc = A1c;
    size_t p = ov;
    float* BS0  = (float*)(base + p); p += 2048;
    float* BS1  = (float*)(base + p); p += 2048;
    float* HN   = (float*)(base + p); p += 131072;   // 128*256*4
    float* HB   = (float*)(base + p); p += 32768;    // 128*64*4
    float* T1c  = (float*)(base + p); p += (size_t)nb * OC * 64 * 4;
    float* ATTc = (float*)(base + p); p += ((size_t)nb * OC * 4 + 255) & ~(size_t)255;
    bf16*  MBb  = (bf16*)(base + p); p += 926720;    // 128*3620*2
    float* H1   = (float*)(base + p); p += 926720;   // 128*1810*4
    bf16* WTa   = (bf16*)(base + p); p += 258048;
    bf16* WTb   = (bf16*)(base + p); p += 258048;
    bf16* A1WB  = (bf16*)(base + p); p += 463360;    // 64*3620*2

    // ---- weight conversions / repacks ----
    wt_repack<<<504, 256, 0, stream>>>(c2aw, WTa);
    wt_repack<<<504, 256, 0, stream>>>(c2bw, WTb);
    cvt4_f16<<<64,   256, 0, stream>>>(whh0, LWf0, 16384);     // 512*128/4
    cvt4_f16<<<64,   256, 0, stream>>>(whh1, LWf1, 16384);
    cvt4_bf16<<<2048, 256, 0, stream>>>(x2,   X2B,   524288);
    cvt4_bf16<<<32,   256, 0, stream>>>(wih0, WIH0B, 8192);
    cvt4_bf16<<<64,   256, 0, stream>>>(wih1, WIH1B, 16384);
    cvt4_bf16<<<227,  256, 0, stream>>>(a1w,  A1WB,  57920);
    bias_sum<<<2, 256, 0, stream>>>(bih0, bhh0, BS0, G4);
    bias_sum<<<2, 256, 0, stream>>>(bih1, bhh1, BS1, G4);

    // ---- LSTM branch (full batch) ----
    gemm_mfma<bf16, bf16, 0><<<dim3(512, 8), 256, 0, stream>>>(
        X2B, IDIM, WIH0B, IDIM, BS0, G0, G4, BB * TT, G4, IDIM);
    lstm_recur<<<BB, 512, 0, stream>>>(G0, LWf0, Y0, HN, 0);
    gemm_mfma<bf16, bf16, 0><<<dim3(512, 8), 256, 0, stream>>>(
        Y0, HD, WIH1B, HD, BS1, G1, G4, BB * TT, G4, HD);
    lstm_recur<<<BB, 512, 0, stream>>>(G1, LWf1, (bf16*)nullptr, HN, HD);

    // hn-part of attention layer 1 (full batch, once; tiny fp32)
    gemm_tn<float, float, 32, 32, 16, 2, 2, 0><<<dim3(4, 2), 256, 0, stream>>>(
        HN, 256, a1w + SS, FF, a1b, HB, ANF, BB, ANF, 256);

    // ---- CNN branch + attention + ctx, chunked over batch (nb rows/chunk) ----
    for (int c0 = 0; c0 < BB; c0 += nb) {
        conv1_kernel<<<dim3(nb, 16), 256, 0, stream>>>(
            x1 + (size_t)c0 * 3 * 64 * 64, c1w, c1b, A1c);
        conv2_mfma<<<dim3(nb, 8), 512, 0, stream>>>(A1c, WTa, c2ab, A2c, W1, W2);
        conv2_mfma<<<dim3(nb, 8), 512, 0, stream>>>(A2c, WTb, c2bb, XDc, W2, W3);
        gemm_mfma<bf16, float, 0><<<dim3(nb * OC / 64, 1), 256, 0, stream>>>(
            XDc, SS, A1WB, FF, nullptr, T1c, ANF, nb * OC, ANF, SS);
        attn_softmax<<<nb, 128, 0, stream>>>(T1c, HB + (size_t)c0 * ANF, a2w, a2b, ATTc);
        ctx_concat<<<dim3(nb, 15), 256, 0, stream>>>(
            XDc, ATTc, HN + (size_t)c0 * 256, MBb + (size_t)c0 * FF);
    }

    // ---- fusion MLP (fc1 converts f32 B during staging) ----
    gemm_mfma<float, float, 1><<<dim3(2, 29), 256, 0, stream>>>(
        MBb, FF, f1w, FF, f1b, H1, HIDN, BB, HIDN, FF);
    fc2_kernel<<<BB / 4, 256, 0, stream>>>(H1, f2w, f2b, out);
}